// Round 6
// baseline (557.494 us; speedup 1.0000x reference)
//
#include <hip/hip_runtime.h>
#include <hip/hip_bf16.h>
#include <math.h>

#define N_NODES 16384
#define DIMV 1024
#define NHEADS 16
#define HEADD 64

typedef __attribute__((ext_vector_type(8))) short short8;
typedef __attribute__((ext_vector_type(4))) float f32x4;
typedef unsigned short ushort_t;

// async global->LDS, 16B per lane; LDS dest is wave-uniform base + lane*16
#define GLD16(gptr, lptr)                                                                 \
  __builtin_amdgcn_global_load_lds((const __attribute__((address_space(1))) void*)(gptr), \
                                   (__attribute__((address_space(3))) void*)(lptr), 16, 0, 0)

// ---------- helpers ----------

__device__ __forceinline__ float waveReduceSum(float v) {
#pragma unroll
  for (int m = 32; m; m >>= 1) v += __shfl_xor(v, m);
  return v;
}

__device__ __forceinline__ float blockReduceSum(float v, float* red) {
  float w = waveReduceSum(v);
  __syncthreads();
  if ((threadIdx.x & 63) == 0) red[threadIdx.x >> 6] = w;
  __syncthreads();
  return red[0] + red[1] + red[2] + red[3];
}

__device__ __forceinline__ float elup1(float z) {
  return z > 0.0f ? z + 1.0f : expm1f(z) + 1.0f;
}

__device__ __forceinline__ float clampabs(float x, float eps) {
  float s = (x >= 0.0f) ? 1.0f : -1.0f;
  return s * fmaxf(fabsf(x), eps);
}

// fp32 -> bf16 bits, RNE
__device__ __forceinline__ ushort_t f2b(float x) {
  unsigned u = __float_as_uint(x);
  unsigned r = (u + 0x7FFFu + ((u >> 16) & 1u)) >> 16;
  return (ushort_t)r;
}
__device__ __forceinline__ float b2f(ushort_t h) {
  return __uint_as_float(((unsigned)h) << 16);
}

// ---------- X -> bf16 + row sumsq (one block per row) ----------
__global__ __launch_bounds__(256) void cvt_norm_kernel(const float* __restrict__ src,
                                                       ushort_t* __restrict__ dst,
                                                       float* __restrict__ rowsq) {
  __shared__ float red[4];
  const int row = blockIdx.x;
  const int t = threadIdx.x;
  float4 x4 = ((const float4*)(src + (size_t)row * DIMV))[t];
  ushort_t h[4] = {f2b(x4.x), f2b(x4.y), f2b(x4.z), f2b(x4.w)};
  ((uint2*)(dst + (size_t)row * DIMV))[t] = *(uint2*)h;
  float s = x4.x * x4.x + x4.y * x4.y + x4.z * x4.z + x4.w * x4.w;
  s = blockReduceSum(s, red);
  if (t == 0) rowsq[row] = s;
}

// ---------- weight transpose -> bf16 (hi, and optional lo residual) ----------
template <bool LO>
__global__ __launch_bounds__(256) void transW_kernel(const float* __restrict__ src,
                                                     ushort_t* __restrict__ hi,
                                                     ushort_t* __restrict__ lo) {
  __shared__ float tile[32][33];
  const int bx = blockIdx.x * 32, by = blockIdx.y * 32;
  const int tx = threadIdx.x & 31, ty = threadIdx.x >> 5;
#pragma unroll
  for (int i = 0; i < 32; i += 8) tile[ty + i][tx] = src[(size_t)(by + ty + i) * DIMV + bx + tx];
  __syncthreads();
#pragma unroll
  for (int i = 0; i < 32; i += 8) {
    float v = tile[tx][ty + i];
    ushort_t h = f2b(v);
    hi[(size_t)(bx + ty + i) * DIMV + by + tx] = h;
    if (LO) lo[(size_t)(bx + ty + i) * DIMV + by + tx] = f2b(v - b2f(h));
  }
}

// ---------- bf16 MFMA GEMM, BK=32, double-buffered 2-phase prefetch, XCD swizzle ----
// A: [M][1024] bf16, Bt: [NB*128 n][1024 k] bf16. 128x128 tile, 4 waves 2x2, 4x4 frags.
// EPI 0: Cq = bf16(acc)                                  (V path)
// EPI 3: cols < 1024 -> Cq = bf16(v1); cols >= 1024 -> Ck = bf16(v2), v2sum atomics (QK fused)
template <int EPI, int NB>
__global__ __launch_bounds__(256) void gemm_bf(const ushort_t* __restrict__ A,
                                               const ushort_t* __restrict__ Bt,
                                               const float* __restrict__ biasQ,
                                               const float* __restrict__ biasK,
                                               const float* __restrict__ denom,
                                               const float* __restrict__ mask,
                                               float* __restrict__ v2sum,
                                               ushort_t* __restrict__ Cq,
                                               ushort_t* __restrict__ Ck) {
  __shared__ ushort_t As[2][128][32];
  __shared__ ushort_t Bs[2][128][32];
  const int bid = blockIdx.x;
  const int swz = (bid & 7) * (NB * 16) + (bid >> 3);
  const int bm = (swz / NB) * 128;
  const int bn = (swz & (NB - 1)) * 128;
  const int t = threadIdx.x;
  const int w = t >> 6, lane = t & 63, l15 = lane & 15;
  const int wr = (w >> 1) * 64, wc = (w & 1) * 64;
  const int kk = (lane >> 4) * 8;

  // two 1KB chunks per wave per operand: chunk c covers lane-linear idx c*64+lane,
  // LDS byte = idx*16 = row*64 + col*2  (row = idx>>2, col = (idx&3)*8)
  const int c0 = w, c1 = 4 + w;
  const int x0 = c0 * 64 + lane, x1 = c1 * 64 + lane;
  const ushort_t* gA0 = A + (size_t)(bm + (x0 >> 2)) * DIMV + (x0 & 3) * 8;
  const ushort_t* gA1 = A + (size_t)(bm + (x1 >> 2)) * DIMV + (x1 & 3) * 8;
  const ushort_t* gB0 = Bt + (size_t)(bn + (x0 >> 2)) * DIMV + (x0 & 3) * 8;
  const ushort_t* gB1 = Bt + (size_t)(bn + (x1 >> 2)) * DIMV + (x1 & 3) * 8;
  ushort_t* lA0 = &As[0][0][0] + c0 * 512;
  ushort_t* lA1 = &As[0][0][0] + c1 * 512;
  ushort_t* lB0 = &Bs[0][0][0] + c0 * 512;
  ushort_t* lB1 = &Bs[0][0][0] + c1 * 512;

#define STAGE_G(buf, k0)                    \
  do {                                      \
    GLD16(gA0 + (k0), lA0 + (buf) * 4096);  \
    GLD16(gA1 + (k0), lA1 + (buf) * 4096);  \
    GLD16(gB0 + (k0), lB0 + (buf) * 4096);  \
    GLD16(gB1 + (k0), lB1 + (buf) * 4096);  \
  } while (0)

  f32x4 acc[4][4];
#pragma unroll
  for (int i = 0; i < 4; ++i)
#pragma unroll
    for (int j = 0; j < 4; ++j) acc[i][j] = (f32x4){0.f, 0.f, 0.f, 0.f};

  STAGE_G(0, 0);
  __syncthreads();  // drains vmcnt(0): buf0 ready
  int cur = 0;
  for (int k0 = 0; k0 < DIMV; k0 += 32) {
    if (k0 + 32 < DIMV) STAGE_G(cur ^ 1, k0 + 32);  // prefetch overlaps compute below
    short8 af[4], bf[4];
#pragma unroll
    for (int i = 0; i < 4; ++i) af[i] = *(const short8*)&As[cur][wr + i * 16 + l15][kk];
#pragma unroll
    for (int j = 0; j < 4; ++j) bf[j] = *(const short8*)&Bs[cur][wc + j * 16 + l15][kk];
#pragma unroll
    for (int i = 0; i < 4; ++i)
#pragma unroll
      for (int j = 0; j < 4; ++j)
        acc[i][j] = __builtin_amdgcn_mfma_f32_16x16x32_bf16(af[i], bf[j], acc[i][j], 0, 0, 0);
    __syncthreads();  // one barrier/iter: drains prefetch (vmcnt) + protects cur buf reuse
    cur ^= 1;
  }
#undef STAGE_G

  // epilogue. C/D layout: col = lane&15, row = (lane>>4)*4 + r
  const int rbase = (lane >> 4) * 4;
  if (EPI == 0) {
#pragma unroll
    for (int j = 0; j < 4; ++j) {
      const int col = bn + wc + j * 16 + l15;
#pragma unroll
      for (int i = 0; i < 4; ++i)
#pragma unroll
        for (int r = 0; r < 4; ++r)
          Cq[(size_t)(bm + wr + i * 16 + rbase + r) * DIMV + col] = f2b(acc[i][j][r]);
    }
  } else {
    const bool isK = (bn >= DIMV);  // block-uniform
    const int h = ((bn + wc) >> 6) & (NHEADS - 1);
    int lc[4];
    float bb[4];
#pragma unroll
    for (int j = 0; j < 4; ++j) {
      lc[j] = (bn + wc + j * 16 + l15) & (DIMV - 1);
      bb[j] = isK ? biasK[lc[j]] : biasQ[lc[j]];
    }
    float csum[4] = {0.f, 0.f, 0.f, 0.f};
#pragma unroll
    for (int i = 0; i < 4; ++i) {
#pragma unroll
      for (int r = 0; r < 4; ++r) {
        const int row = bm + wr + i * 16 + rbase + r;
        const float invdp = 1.0f / denom[(size_t)h * N_NODES + row];
        float den = 0.f, mk = 0.f;
        if (isK) {
          den = clampabs(2.0f * invdp - 1.0f, 1e-10f);
          mk = mask[row];
        }
#pragma unroll
        for (int j = 0; j < 4; ++j) {
          float val = elup1((acc[i][j][r] + bb[j]) * invdp);
          if (isK) {
            val = den * val * mk;
            csum[j] += val;
            Ck[(size_t)row * DIMV + lc[j]] = f2b(val);
          } else {
            Cq[(size_t)row * DIMV + lc[j]] = f2b(val);
          }
        }
      }
    }
    if (isK) {
#pragma unroll
      for (int j = 0; j < 4; ++j) atomicAdd(&v2sum[lc[j]], csum[j]);
    }
  }
}

// ---------- fused 3-term split GEMM: C = bf16(AhiBhi + AloBhi + AhiBlo), dbuf 2-phase ----------
__global__ __launch_bounds__(256) void gemm_split3(const ushort_t* __restrict__ Ahi,
                                                   const ushort_t* __restrict__ Alo,
                                                   const ushort_t* __restrict__ Bhi,
                                                   const ushort_t* __restrict__ Blo,
                                                   ushort_t* __restrict__ C) {
  __shared__ ushort_t AsH[2][128][32], AsL[2][128][32], BsH[2][128][32], BsL[2][128][32];
  const int bid = blockIdx.x;
  const int swz = (bid & 7) * 128 + (bid >> 3);  // nwg = 1024
  const int bm = (swz >> 3) * 128;
  const int bn = (swz & 7) * 128;
  const int t = threadIdx.x;
  const int w = t >> 6, lane = t & 63, l15 = lane & 15;
  const int wr = (w >> 1) * 64, wc = (w & 1) * 64;
  const int kk = (lane >> 4) * 8;

  const int c0 = w, c1 = 4 + w;
  const int x0 = c0 * 64 + lane, x1 = c1 * 64 + lane;
  const size_t go0A = (size_t)(bm + (x0 >> 2)) * DIMV + (x0 & 3) * 8;
  const size_t go1A = (size_t)(bm + (x1 >> 2)) * DIMV + (x1 & 3) * 8;
  const size_t go0B = (size_t)(bn + (x0 >> 2)) * DIMV + (x0 & 3) * 8;
  const size_t go1B = (size_t)(bn + (x1 >> 2)) * DIMV + (x1 & 3) * 8;
  ushort_t* lh0A = &AsH[0][0][0] + c0 * 512;
  ushort_t* lh1A = &AsH[0][0][0] + c1 * 512;
  ushort_t* ll0A = &AsL[0][0][0] + c0 * 512;
  ushort_t* ll1A = &AsL[0][0][0] + c1 * 512;
  ushort_t* lh0B = &BsH[0][0][0] + c0 * 512;
  ushort_t* lh1B = &BsH[0][0][0] + c1 * 512;
  ushort_t* ll0B = &BsL[0][0][0] + c0 * 512;
  ushort_t* ll1B = &BsL[0][0][0] + c1 * 512;

#define STAGE_S(buf, k0)                         \
  do {                                           \
    GLD16(Ahi + go0A + (k0), lh0A + (buf) * 4096); \
    GLD16(Ahi + go1A + (k0), lh1A + (buf) * 4096); \
    GLD16(Alo + go0A + (k0), ll0A + (buf) * 4096); \
    GLD16(Alo + go1A + (k0), ll1A + (buf) * 4096); \
    GLD16(Bhi + go0B + (k0), lh0B + (buf) * 4096); \
    GLD16(Bhi + go1B + (k0), lh1B + (buf) * 4096); \
    GLD16(Blo + go0B + (k0), ll0B + (buf) * 4096); \
    GLD16(Blo + go1B + (k0), ll1B + (buf) * 4096); \
  } while (0)

  f32x4 acc[4][4];
#pragma unroll
  for (int i = 0; i < 4; ++i)
#pragma unroll
    for (int j = 0; j < 4; ++j) acc[i][j] = (f32x4){0.f, 0.f, 0.f, 0.f};

  STAGE_S(0, 0);
  __syncthreads();
  int cur = 0;
  for (int k0 = 0; k0 < DIMV; k0 += 32) {
    if (k0 + 32 < DIMV) STAGE_S(cur ^ 1, k0 + 32);
    short8 afH[4], afL[4], bfH[4], bfL[4];
#pragma unroll
    for (int i = 0; i < 4; ++i) {
      afH[i] = *(const short8*)&AsH[cur][wr + i * 16 + l15][kk];
      afL[i] = *(const short8*)&AsL[cur][wr + i * 16 + l15][kk];
    }
#pragma unroll
    for (int j = 0; j < 4; ++j) {
      bfH[j] = *(const short8*)&BsH[cur][wc + j * 16 + l15][kk];
      bfL[j] = *(const short8*)&BsL[cur][wc + j * 16 + l15][kk];
    }
#pragma unroll
    for (int i = 0; i < 4; ++i)
#pragma unroll
      for (int j = 0; j < 4; ++j) {
        acc[i][j] = __builtin_amdgcn_mfma_f32_16x16x32_bf16(afH[i], bfH[j], acc[i][j], 0, 0, 0);
        acc[i][j] = __builtin_amdgcn_mfma_f32_16x16x32_bf16(afL[i], bfH[j], acc[i][j], 0, 0, 0);
        acc[i][j] = __builtin_amdgcn_mfma_f32_16x16x32_bf16(afH[i], bfL[j], acc[i][j], 0, 0, 0);
      }
    __syncthreads();
    cur ^= 1;
  }
#undef STAGE_S

  const int rbase = (lane >> 4) * 4;
#pragma unroll
  for (int j = 0; j < 4; ++j) {
    const int col = bn + wc + j * 16 + l15;
#pragma unroll
    for (int i = 0; i < 4; ++i)
#pragma unroll
      for (int r = 0; r < 4; ++r)
        C[(size_t)(bm + wr + i * 16 + rbase + r) * DIMV + col] = f2b(acc[i][j][r]);
  }
}

// ---------- row transform: mobius_matvec tail + kappa_relu (bf16 msrc, precomputed ||x||^2) ----------
template <bool BFDST>
__global__ __launch_bounds__(256) void rowtrans_kernel(const ushort_t* __restrict__ msrc,
                                                       const float* __restrict__ rowsq,
                                                       void* __restrict__ dstv,
                                                       float* __restrict__ denom) {
  __shared__ float red[4];
  __shared__ float orow[DIMV];
  const int row = blockIdx.x;
  const int t = threadIdx.x;
  uint2 mraw = ((const uint2*)(msrc + (size_t)row * DIMV))[t];
  ushort_t* mh = (ushort_t*)&mraw;
  float4 m4 = make_float4(b2f(mh[0]), b2f(mh[1]), b2f(mh[2]), b2f(mh[3]));
  float sm = m4.x * m4.x + m4.y * m4.y + m4.z * m4.z + m4.w * m4.w;
  sm = blockReduceSum(sm, red);
  float sx = rowsq[row];

  float xn = fmaxf(sqrtf(sx), 1e-15f);
  float mxn = fmaxf(sqrtf(sm), 1e-15f);
  float cx = fminf(xn, 1.0f - 1e-7f);
  float t1 = tanhf(mxn / xn * atanhf(cx));
  float s1 = t1 / mxn;

  float yn = fmaxf(fabsf(t1), 1e-15f);
  float a = atanhf(fminf(yn, 1.0f - 1e-7f)) / yn;
  float k1 = a * s1;
  float4 u = make_float4(fmaxf(k1 * m4.x, 0.0f), fmaxf(k1 * m4.y, 0.0f),
                         fmaxf(k1 * m4.z, 0.0f), fmaxf(k1 * m4.w, 0.0f));
  float su = u.x * u.x + u.y * u.y + u.z * u.z + u.w * u.w;
  su = blockReduceSum(su, red);

  float un = fmaxf(sqrtf(su), 1e-15f);
  float t2 = tanhf(un);
  float s2 = t2 / un;
  if (t2 > 0.996f) s2 *= 0.996f / t2;
  float4 o = make_float4(s2 * u.x, s2 * u.y, s2 * u.z, s2 * u.w);
  if (BFDST) {
    ushort_t h[4] = {f2b(o.x), f2b(o.y), f2b(o.z), f2b(o.w)};
    ((uint2*)((ushort_t*)dstv + (size_t)row * DIMV))[t] = *(uint2*)h;
  } else {
    ((float4*)((float*)dstv + (size_t)row * DIMV))[t] = o;
  }

  if (denom) {
    ((float4*)orow)[t] = o;
    __syncthreads();
    if (t < NHEADS) {
      float s = 0.0f;
#pragma unroll
      for (int i = 0; i < HEADD; ++i) {
        float v = orow[t * HEADD + i];
        s = fmaf(v, v, s);
      }
      denom[t * N_NODES + row] = fmaxf(1.0f - s, 1e-15f);
    }
  }
}

// ---------- ctxT[h][e][d] = sum_n v2[h,n,d] * (gamma/den * mask * V)[h,n,e]  (v2,V bf16) ----------
__global__ __launch_bounds__(256) void context_kernel(const ushort_t* __restrict__ v2buf,
                                                      const ushort_t* __restrict__ vbuf,
                                                      const float* __restrict__ denom,
                                                      const float* __restrict__ mask,
                                                      float* __restrict__ ctxT) {
  __shared__ float s2[64][65];
  __shared__ float sx[64][65];
  const int h = blockIdx.y;
  const int t = threadIdx.x;
  const int d0 = (t >> 4) * 4;
  const int e0 = (t & 15) * 4;
  float acc[4][4];
#pragma unroll
  for (int i = 0; i < 4; ++i)
#pragma unroll
    for (int j = 0; j < 4; ++j) acc[i][j] = 0.0f;

  const int rbase = blockIdx.x * 512;
  for (int c = 0; c < 8; ++c) {
#pragma unroll
    for (int i = 0; i < 4; ++i) {
      int f = i * 256 + t;
      int r = f >> 4;
      int cc = (f & 15) * 4;
      int row = rbase + c * 64 + r;
      uint2 araw = *(const uint2*)(v2buf + (size_t)row * DIMV + h * HEADD + cc);
      ushort_t* ah = (ushort_t*)&araw;
      s2[r][cc + 0] = b2f(ah[0]); s2[r][cc + 1] = b2f(ah[1]);
      s2[r][cc + 2] = b2f(ah[2]); s2[r][cc + 3] = b2f(ah[3]);
      float dp = denom[(size_t)h * N_NODES + row];
      float gamma = 2.0f / dp;
      float den = clampabs(gamma - 1.0f, 1e-10f);
      float c1 = gamma / den * mask[row];
      uint2 braw = *(const uint2*)(vbuf + (size_t)row * DIMV + h * HEADD + cc);
      ushort_t* bh = (ushort_t*)&braw;
      sx[r][cc + 0] = c1 * b2f(bh[0]); sx[r][cc + 1] = c1 * b2f(bh[1]);
      sx[r][cc + 2] = c1 * b2f(bh[2]); sx[r][cc + 3] = c1 * b2f(bh[3]);
    }
    __syncthreads();
    for (int r = 0; r < 64; ++r) {
      float av[4], bv[4];
#pragma unroll
      for (int i = 0; i < 4; ++i) av[i] = s2[r][d0 + i];
#pragma unroll
      for (int j = 0; j < 4; ++j) bv[j] = sx[r][e0 + j];
#pragma unroll
      for (int i = 0; i < 4; ++i)
#pragma unroll
        for (int j = 0; j < 4; ++j) acc[i][j] = fmaf(av[i], bv[j], acc[i][j]);
    }
    __syncthreads();
  }
#pragma unroll
  for (int i = 0; i < 4; ++i)
#pragma unroll
    for (int j = 0; j < 4; ++j)
      atomicAdd(&ctxT[h * 4096 + (e0 + j) * 64 + (d0 + i)], acc[i][j]);
}

// ---------- out (MFMA): [out|D] = v1 @ [ctx|v2sum]; tail; emit combHi/Lo + rownorm atomics ----------
__global__ __launch_bounds__(256) void out_mfma_kernel(const ushort_t* __restrict__ v1bf,
                                                       const float* __restrict__ v2sum,
                                                       const float* __restrict__ ctxT,
                                                       ushort_t* __restrict__ combHi,
                                                       ushort_t* __restrict__ combLo,
                                                       float* __restrict__ combnorm) {
  __shared__ ushort_t Blds[80][88];
  const int h = blockIdx.y;
  const int bm = blockIdx.x * 256;
  const int t = threadIdx.x;
  const int w = t >> 6, lane = t & 63, l15 = lane & 15;
  const int kk = (lane >> 4) * 8;

  for (int idx = t; idx < 80 * 64; idx += 256) {
    int e = idx >> 6, d = idx & 63;
    float v = 0.0f;
    if (e < 64) v = ctxT[h * 4096 + e * 64 + d];
    else if (e == 64) v = v2sum[h * 64 + d];
    Blds[e][d] = f2b(v);
  }
  __syncthreads();

  f32x4 acc[4][5];
#pragma unroll
  for (int i = 0; i < 4; ++i)
#pragma unroll
    for (int j = 0; j < 5; ++j) acc[i][j] = (f32x4){0.f, 0.f, 0.f, 0.f};
#pragma unroll
  for (int ks = 0; ks < 2; ++ks) {
    short8 bfr[5];
#pragma unroll
    for (int j = 0; j < 5; ++j) bfr[j] = *(const short8*)&Blds[j * 16 + l15][ks * 32 + kk];
#pragma unroll
    for (int i = 0; i < 4; ++i) {
      short8 af = *(const short8*)(v1bf + (size_t)(bm + w * 64 + i * 16 + l15) * DIMV +
                                   h * HEADD + ks * 32 + kk);
#pragma unroll
      for (int j = 0; j < 5; ++j)
        acc[i][j] = __builtin_amdgcn_mfma_f32_16x16x32_bf16(af, bfr[j], acc[i][j], 0, 0, 0);
    }
  }

  const int g4 = (lane >> 4) * 4;
#pragma unroll
  for (int i = 0; i < 4; ++i) {
#pragma unroll
    for (int r = 0; r < 4; ++r) {
      const int row = bm + w * 64 + i * 16 + g4 + r;
      float D = __shfl(acc[i][4][r], lane & 48);
      float Dinv = 1.0f / (D == 0.0f ? 1e-5f : D);
      float o[4];
      float s = 0.0f;
#pragma unroll
      for (int j = 0; j < 4; ++j) {
        o[j] = acc[i][j][r] * Dinv;
        s = fmaf(o[j], o[j], s);
      }
      s += __shfl_xor(s, 1); s += __shfl_xor(s, 2);
      s += __shfl_xor(s, 4); s += __shfl_xor(s, 8);
      float n1 = fmaxf(sqrtf(s), 1e-15f);
      float sc = 1.0f;
      if (n1 > 0.996f) sc = 0.996f / n1;
      float xn = fmaxf(fminf(n1, 0.996f), 1e-15f);
      float cx = fminf(xn, 1.0f - 1e-7f);
      float t2 = tanhf(0.5f * atanhf(cx));
      sc *= t2 / xn;
      if (t2 > 0.996f) sc *= 0.996f / t2;
      if (l15 == 0) atomicAdd(&combnorm[row], s * sc * sc);
#pragma unroll
      for (int j = 0; j < 4; ++j) {
        float ov = o[j] * sc;
        size_t off = (size_t)row * DIMV + h * HEADD + j * 16 + l15;
        ushort_t hi = f2b(ov);
        combHi[off] = hi;
        combLo[off] = f2b(ov - b2f(hi));
      }
    }
  }
}

// ---------- launch ----------

extern "C" void kernel_launch(void* const* d_in, const int* in_sizes, int n_in,
                              void* d_out, int out_size, void* d_ws, size_t ws_size,
                              hipStream_t stream) {
  const float* X = (const float*)d_in[0];
  const float* mask = (const float*)d_in[1];
  const float* Wq = (const float*)d_in[2];
  const float* bq = (const float*)d_in[3];
  const float* Wk = (const float*)d_in[4];
  const float* bk = (const float*)d_in[5];
  const float* Wv = (const float*)d_in[6];
  const float* Wff = (const float*)d_in[7];
  float* out = (float*)d_out;

  const size_t MAT = (size_t)N_NODES * DIMV;
  char* p = (char*)d_ws;
  // R1 (64MB): first half v1bf (QK epi out); second half mxV bf16, later combnorm
  ushort_t* v1bf = (ushort_t*)p;
  ushort_t* mxV = (ushort_t*)(p + MAT * 2);
  float* combnorm = (float*)(p + MAT * 2);
  p += MAT * 4;
  // R2 (64MB): xnormsq (early) / v2bf (QK epi out) / combHi+combLo (after context)
  float* xnormsq = (float*)p;
  ushort_t* v2bf = (ushort_t*)p;
  ushort_t* combHi = (ushort_t*)p;
  ushort_t* combLo = combHi + MAT;
  p += MAT * 4;
  // R3 (32MB): Vbf; later WffHi/WffLo
  ushort_t* Vbf = (ushort_t*)p;
  ushort_t* WffHi = Vbf;
  ushort_t* WffLo = Vbf + (size_t)DIMV * DIMV;
  p += MAT * 2;
  // R4 (32MB): Xbf; later outBf (split3 out)
  ushort_t* Xbf = (ushort_t*)p;
  ushort_t* outBf = Xbf;
  p += MAT * 2;
  float* denom = (float*)p;  p += (size_t)NHEADS * N_NODES * 4;
  float* v2sum = (float*)p;  p += 1024 * 4;
  float* ctxT = (float*)p;   p += (size_t)NHEADS * 4096 * 4;
  const size_t need = (size_t)(p - (char*)d_ws);
  if (ws_size < need) return;

  // W^T bf16 scratch inside d_out (free until the final rowtrans writes it):
  ushort_t* Wt = (ushort_t*)d_out;            // Wv^T, later Wq^T (rows 0..1023)
  ushort_t* WtK = Wt + (size_t)DIMV * DIMV;   // Wk^T (rows 1024..2047 of stacked QK)

  dim3 tgrid(32, 32);

  cvt_norm_kernel<<<N_NODES, 256, 0, stream>>>(X, Xbf, xnormsq);
  // V path: mxV bf16, then rowtrans -> Vbf + denom
  transW_kernel<false><<<tgrid, 256, 0, stream>>>(Wv, Wt, nullptr);
  gemm_bf<0, 8><<<1024, 256, 0, stream>>>(Xbf, Wt, nullptr, nullptr, nullptr, nullptr,
                                          nullptr, mxV, nullptr);
  rowtrans_kernel<true><<<N_NODES, 256, 0, stream>>>(mxV, xnormsq, Vbf, denom);
  // zero accumulators (v2sum+ctxT contiguous; combnorm over dead mxV)
  hipMemsetAsync(v2sum, 0, (1024 + 4096 * NHEADS) * sizeof(float), stream);
  hipMemsetAsync(combnorm, 0, N_NODES * sizeof(float), stream);
  // QK fused: stacked [Wq^T; Wk^T], epilogue emits v1 (cols<1024) and v2 + v2sum (cols>=1024)
  transW_kernel<false><<<tgrid, 256, 0, stream>>>(Wq, Wt, nullptr);
  transW_kernel<false><<<tgrid, 256, 0, stream>>>(Wk, WtK, nullptr);
  gemm_bf<3, 16><<<2048, 256, 0, stream>>>(Xbf, Wt, bq, bk, denom, mask, v2sum, v1bf, v2bf);
  // context (transposed output)
  context_kernel<<<dim3(32, NHEADS), 256, 0, stream>>>(v2bf, Vbf, denom, mask, ctxT);
  // attention out -> combHi/Lo + row norms
  out_mfma_kernel<<<dim3(N_NODES / 256, NHEADS), 256, 0, stream>>>(v1bf, v2sum, ctxT, combHi,
                                                                   combLo, combnorm);
  // final: fused 3-term split GEMM -> outBf, then rowtrans -> d_out
  transW_kernel<true><<<tgrid, 256, 0, stream>>>(Wff, WffHi, WffLo);
  gemm_split3<<<1024, 256, 0, stream>>>(combHi, combLo, WffHi, WffLo, outBf);
  rowtrans_kernel<false><<<N_NODES, 256, 0, stream>>>(outBf, combnorm, out, nullptr);
}

// Round 7
// 523.111 us; speedup vs baseline: 1.0657x; 1.0657x over previous
//
#include <hip/hip_runtime.h>
#include <hip/hip_bf16.h>
#include <math.h>

#define N_NODES 16384
#define DIMV 1024
#define NHEADS 16
#define HEADD 64

typedef __attribute__((ext_vector_type(8))) short short8;
typedef __attribute__((ext_vector_type(4))) float f32x4;
typedef unsigned short ushort_t;

// async global->LDS, 16B per lane; LDS dest is wave-uniform base + lane*16
#define GLD16(gptr, lptr)                                                                 \
  __builtin_amdgcn_global_load_lds((const __attribute__((address_space(1))) void*)(gptr), \
                                   (__attribute__((address_space(3))) void*)(lptr), 16, 0, 0)

// ---------- helpers ----------

__device__ __forceinline__ float waveReduceSum(float v) {
#pragma unroll
  for (int m = 32; m; m >>= 1) v += __shfl_xor(v, m);
  return v;
}

__device__ __forceinline__ float blockReduceSum(float v, float* red) {
  float w = waveReduceSum(v);
  __syncthreads();
  if ((threadIdx.x & 63) == 0) red[threadIdx.x >> 6] = w;
  __syncthreads();
  return red[0] + red[1] + red[2] + red[3];
}

__device__ __forceinline__ float elup1(float z) {
  return z > 0.0f ? z + 1.0f : expm1f(z) + 1.0f;
}

__device__ __forceinline__ float clampabs(float x, float eps) {
  float s = (x >= 0.0f) ? 1.0f : -1.0f;
  return s * fmaxf(fabsf(x), eps);
}

// fp32 -> bf16 bits, RNE
__device__ __forceinline__ ushort_t f2b(float x) {
  unsigned u = __float_as_uint(x);
  unsigned r = (u + 0x7FFFu + ((u >> 16) & 1u)) >> 16;
  return (ushort_t)r;
}
__device__ __forceinline__ float b2f(ushort_t h) {
  return __uint_as_float(((unsigned)h) << 16);
}

// ---------- X -> bf16 + row sumsq (one block per row) ----------
__global__ __launch_bounds__(256) void cvt_norm_kernel(const float* __restrict__ src,
                                                       ushort_t* __restrict__ dst,
                                                       float* __restrict__ rowsq) {
  __shared__ float red[4];
  const int row = blockIdx.x;
  const int t = threadIdx.x;
  float4 x4 = ((const float4*)(src + (size_t)row * DIMV))[t];
  ushort_t h[4] = {f2b(x4.x), f2b(x4.y), f2b(x4.z), f2b(x4.w)};
  ((uint2*)(dst + (size_t)row * DIMV))[t] = *(uint2*)h;
  float s = x4.x * x4.x + x4.y * x4.y + x4.z * x4.z + x4.w * x4.w;
  s = blockReduceSum(s, red);
  if (t == 0) rowsq[row] = s;
}

// ---------- weight transpose -> bf16 (hi, and optional lo residual) ----------
template <bool LO>
__global__ __launch_bounds__(256) void transW_kernel(const float* __restrict__ src,
                                                     ushort_t* __restrict__ hi,
                                                     ushort_t* __restrict__ lo) {
  __shared__ float tile[32][33];
  const int bx = blockIdx.x * 32, by = blockIdx.y * 32;
  const int tx = threadIdx.x & 31, ty = threadIdx.x >> 5;
#pragma unroll
  for (int i = 0; i < 32; i += 8) tile[ty + i][tx] = src[(size_t)(by + ty + i) * DIMV + bx + tx];
  __syncthreads();
#pragma unroll
  for (int i = 0; i < 32; i += 8) {
    float v = tile[tx][ty + i];
    ushort_t h = f2b(v);
    hi[(size_t)(bx + ty + i) * DIMV + by + tx] = h;
    if (LO) lo[(size_t)(bx + ty + i) * DIMV + by + tx] = f2b(v - b2f(h));
  }
}

// ---------- bf16 MFMA GEMM, 256x256 tile, BK=64, 8 waves (2Mx4N), dbuf 2-phase ----------
// A: [M][1024] bf16, Bt: [NB*256 n][1024 k] bf16. Per wave: 128x64 out = acc[8][4].
// EPI 0: Cq = bf16(acc)                                  (V path)
// EPI 3: cols < 1024 -> Cq = bf16(v1); cols >= 1024 -> Ck = bf16(v2), v2sum atomics (QK fused)
template <int EPI, int NB>
__global__ __launch_bounds__(512, 2) void gemm_bf(const ushort_t* __restrict__ A,
                                                  const ushort_t* __restrict__ Bt,
                                                  const float* __restrict__ biasQ,
                                                  const float* __restrict__ biasK,
                                                  const float* __restrict__ denom,
                                                  const float* __restrict__ mask,
                                                  float* __restrict__ v2sum,
                                                  ushort_t* __restrict__ Cq,
                                                  ushort_t* __restrict__ Ck) {
  __shared__ ushort_t As[2][256 * 64];  // 32 KB per buf
  __shared__ ushort_t Bs[2][256 * 64];
  const int bid = blockIdx.x;
  const int nwg = NB * 64;  // (16384/256) * NB
  const int swz = (bid & 7) * (nwg / 8) + (bid >> 3);  // XCD-contiguous chunks
  const int bm = (swz / NB) * 256;
  const int bn = (swz % NB) * 256;
  const int t = threadIdx.x;
  const int w = t >> 6, lane = t & 63, l15 = lane & 15;
  const int wr = (w >> 2) * 128;   // wave row base (2 M-groups)
  const int wcn = (w & 3) * 64;    // wave col base (4 N-groups)
  const int kk = (lane >> 4) * 8;

  // staging: 32 chunks of 1KB (8 rows x 128B) per operand; wave w takes chunks w+8c.
  const int rowin = lane >> 3;
  const int ksh = (lane & 7) * 8;
  const ushort_t *gA[4], *gB[4];
  int lofs[4];
#pragma unroll
  for (int c = 0; c < 4; ++c) {
    const int ch = w + 8 * c;
    lofs[c] = ch * 512;
    gA[c] = A + (size_t)(bm + ch * 8 + rowin) * DIMV + ksh;
    gB[c] = Bt + (size_t)(bn + ch * 8 + rowin) * DIMV + ksh;
  }

#define STAGE_G(buf, k0)                              \
  do {                                                \
    _Pragma("unroll") for (int c = 0; c < 4; ++c) {   \
      GLD16(gA[c] + (k0), &As[buf][lofs[c]]);         \
      GLD16(gB[c] + (k0), &Bs[buf][lofs[c]]);         \
    }                                                 \
  } while (0)

  f32x4 acc[8][4];
#pragma unroll
  for (int i = 0; i < 8; ++i)
#pragma unroll
    for (int j = 0; j < 4; ++j) acc[i][j] = (f32x4){0.f, 0.f, 0.f, 0.f};

  STAGE_G(0, 0);
  __syncthreads();  // drains vmcnt(0): buf0 ready
  int cur = 0;
  for (int k0 = 0; k0 < DIMV; k0 += 64) {
    if (k0 + 64 < DIMV) STAGE_G(cur ^ 1, k0 + 64);  // prefetch flies under compute
#pragma unroll
    for (int ks = 0; ks < 2; ++ks) {
      short8 bf[4];
#pragma unroll
      for (int j = 0; j < 4; ++j)
        bf[j] = *(const short8*)&Bs[cur][(wcn + j * 16 + l15) * 64 + ks * 32 + kk];
#pragma unroll
      for (int i = 0; i < 8; ++i) {
        short8 af = *(const short8*)&As[cur][(wr + i * 16 + l15) * 64 + ks * 32 + kk];
#pragma unroll
        for (int j = 0; j < 4; ++j)
          acc[i][j] = __builtin_amdgcn_mfma_f32_16x16x32_bf16(af, bf[j], acc[i][j], 0, 0, 0);
      }
    }
    __syncthreads();  // one barrier/K-tile: drains prefetch + protects buf reuse
    cur ^= 1;
  }
#undef STAGE_G

  // epilogue. C/D layout: col = lane&15, row = (lane>>4)*4 + r
  const int rbase = (lane >> 4) * 4;
  if (EPI == 0) {
#pragma unroll
    for (int j = 0; j < 4; ++j) {
      const int col = bn + wcn + j * 16 + l15;
#pragma unroll
      for (int i = 0; i < 8; ++i)
#pragma unroll
        for (int r = 0; r < 4; ++r)
          Cq[(size_t)(bm + wr + i * 16 + rbase + r) * DIMV + col] = f2b(acc[i][j][r]);
    }
  } else {
    const bool isK = (bn >= DIMV);  // block-uniform (bn multiple of 256)
    const int h = ((bn + wcn) >> 6) & (NHEADS - 1);
    int lc[4];
    float bb[4];
#pragma unroll
    for (int j = 0; j < 4; ++j) {
      lc[j] = (bn + wcn + j * 16 + l15) & (DIMV - 1);
      bb[j] = isK ? biasK[lc[j]] : biasQ[lc[j]];
    }
    float csum[4] = {0.f, 0.f, 0.f, 0.f};
#pragma unroll
    for (int i = 0; i < 8; ++i) {
#pragma unroll
      for (int r = 0; r < 4; ++r) {
        const int row = bm + wr + i * 16 + rbase + r;
        const float invdp = 1.0f / denom[(size_t)h * N_NODES + row];
        float den = 0.f, mk = 0.f;
        if (isK) {
          den = clampabs(2.0f * invdp - 1.0f, 1e-10f);
          mk = mask[row];
        }
#pragma unroll
        for (int j = 0; j < 4; ++j) {
          float val = elup1((acc[i][j][r] + bb[j]) * invdp);
          if (isK) {
            val = den * val * mk;
            csum[j] += val;
            Ck[(size_t)row * DIMV + lc[j]] = f2b(val);
          } else {
            Cq[(size_t)row * DIMV + lc[j]] = f2b(val);
          }
        }
      }
    }
    if (isK) {
#pragma unroll
      for (int j = 0; j < 4; ++j) atomicAdd(&v2sum[lc[j]], csum[j]);
    }
  }
}

// ---------- fused 3-term split GEMM: C = bf16(AhiBhi + AloBhi + AhiBlo) ----------
// 256x256 tile, BK=32, 8 waves, dbuf 2-phase. 4 staged arrays x 16KB x 2buf = 128 KB LDS.
__global__ __launch_bounds__(512, 2) void gemm_split3(const ushort_t* __restrict__ Ahi,
                                                      const ushort_t* __restrict__ Alo,
                                                      const ushort_t* __restrict__ Bhi,
                                                      const ushort_t* __restrict__ Blo,
                                                      ushort_t* __restrict__ C) {
  __shared__ ushort_t AsH[2][256 * 32], AsL[2][256 * 32];
  __shared__ ushort_t BsH[2][256 * 32], BsL[2][256 * 32];
  const int bid = blockIdx.x;
  const int swz = (bid & 7) * 32 + (bid >> 3);  // nwg = 256
  const int bm = (swz >> 2) * 256;
  const int bn = (swz & 3) * 256;
  const int t = threadIdx.x;
  const int w = t >> 6, lane = t & 63, l15 = lane & 15;
  const int wr = (w >> 2) * 128;
  const int wcn = (w & 3) * 64;
  const int kk = (lane >> 4) * 8;

  // staging: 16 chunks of 1KB (16 rows x 64B) per array; wave w takes chunks w+8c, c in {0,1}.
  const int rowin = lane >> 2;
  const int ksh = (lane & 3) * 8;
  size_t goA[2], goB[2];
  int lofs[2];
#pragma unroll
  for (int c = 0; c < 2; ++c) {
    const int ch = w + 8 * c;
    lofs[c] = ch * 512;
    goA[c] = (size_t)(bm + ch * 16 + rowin) * DIMV + ksh;
    goB[c] = (size_t)(bn + ch * 16 + rowin) * DIMV + ksh;
  }

#define STAGE_S(buf, k0)                              \
  do {                                                \
    _Pragma("unroll") for (int c = 0; c < 2; ++c) {   \
      GLD16(Ahi + goA[c] + (k0), &AsH[buf][lofs[c]]); \
      GLD16(Alo + goA[c] + (k0), &AsL[buf][lofs[c]]); \
      GLD16(Bhi + goB[c] + (k0), &BsH[buf][lofs[c]]); \
      GLD16(Blo + goB[c] + (k0), &BsL[buf][lofs[c]]); \
    }                                                 \
  } while (0)

  f32x4 acc[8][4];
#pragma unroll
  for (int i = 0; i < 8; ++i)
#pragma unroll
    for (int j = 0; j < 4; ++j) acc[i][j] = (f32x4){0.f, 0.f, 0.f, 0.f};

  STAGE_S(0, 0);
  __syncthreads();
  int cur = 0;
  for (int k0 = 0; k0 < DIMV; k0 += 32) {
    if (k0 + 32 < DIMV) STAGE_S(cur ^ 1, k0 + 32);
    short8 bfH[4], bfL[4];
#pragma unroll
    for (int j = 0; j < 4; ++j) {
      bfH[j] = *(const short8*)&BsH[cur][(wcn + j * 16 + l15) * 32 + kk];
      bfL[j] = *(const short8*)&BsL[cur][(wcn + j * 16 + l15) * 32 + kk];
    }
#pragma unroll
    for (int i = 0; i < 8; ++i) {
      short8 afH = *(const short8*)&AsH[cur][(wr + i * 16 + l15) * 32 + kk];
      short8 afL = *(const short8*)&AsL[cur][(wr + i * 16 + l15) * 32 + kk];
#pragma unroll
      for (int j = 0; j < 4; ++j) {
        acc[i][j] = __builtin_amdgcn_mfma_f32_16x16x32_bf16(afH, bfH[j], acc[i][j], 0, 0, 0);
        acc[i][j] = __builtin_amdgcn_mfma_f32_16x16x32_bf16(afL, bfH[j], acc[i][j], 0, 0, 0);
        acc[i][j] = __builtin_amdgcn_mfma_f32_16x16x32_bf16(afH, bfL[j], acc[i][j], 0, 0, 0);
      }
    }
    __syncthreads();
    cur ^= 1;
  }
#undef STAGE_S

  const int rbase = (lane >> 4) * 4;
#pragma unroll
  for (int j = 0; j < 4; ++j) {
    const int col = bn + wcn + j * 16 + l15;
#pragma unroll
    for (int i = 0; i < 8; ++i)
#pragma unroll
      for (int r = 0; r < 4; ++r)
        C[(size_t)(bm + wr + i * 16 + rbase + r) * DIMV + col] = f2b(acc[i][j][r]);
  }
}

// ---------- row transform: mobius_matvec tail + kappa_relu (bf16 msrc, precomputed ||x||^2) ----------
template <bool BFDST>
__global__ __launch_bounds__(256) void rowtrans_kernel(const ushort_t* __restrict__ msrc,
                                                       const float* __restrict__ rowsq,
                                                       void* __restrict__ dstv,
                                                       float* __restrict__ denom) {
  __shared__ float red[4];
  __shared__ float orow[DIMV];
  const int row = blockIdx.x;
  const int t = threadIdx.x;
  uint2 mraw = ((const uint2*)(msrc + (size_t)row * DIMV))[t];
  ushort_t* mh = (ushort_t*)&mraw;
  float4 m4 = make_float4(b2f(mh[0]), b2f(mh[1]), b2f(mh[2]), b2f(mh[3]));
  float sm = m4.x * m4.x + m4.y * m4.y + m4.z * m4.z + m4.w * m4.w;
  sm = blockReduceSum(sm, red);
  float sx = rowsq[row];

  float xn = fmaxf(sqrtf(sx), 1e-15f);
  float mxn = fmaxf(sqrtf(sm), 1e-15f);
  float cx = fminf(xn, 1.0f - 1e-7f);
  float t1 = tanhf(mxn / xn * atanhf(cx));
  float s1 = t1 / mxn;

  float yn = fmaxf(fabsf(t1), 1e-15f);
  float a = atanhf(fminf(yn, 1.0f - 1e-7f)) / yn;
  float k1 = a * s1;
  float4 u = make_float4(fmaxf(k1 * m4.x, 0.0f), fmaxf(k1 * m4.y, 0.0f),
                         fmaxf(k1 * m4.z, 0.0f), fmaxf(k1 * m4.w, 0.0f));
  float su = u.x * u.x + u.y * u.y + u.z * u.z + u.w * u.w;
  su = blockReduceSum(su, red);

  float un = fmaxf(sqrtf(su), 1e-15f);
  float t2 = tanhf(un);
  float s2 = t2 / un;
  if (t2 > 0.996f) s2 *= 0.996f / t2;
  float4 o = make_float4(s2 * u.x, s2 * u.y, s2 * u.z, s2 * u.w);
  if (BFDST) {
    ushort_t h[4] = {f2b(o.x), f2b(o.y), f2b(o.z), f2b(o.w)};
    ((uint2*)((ushort_t*)dstv + (size_t)row * DIMV))[t] = *(uint2*)h;
  } else {
    ((float4*)((float*)dstv + (size_t)row * DIMV))[t] = o;
  }

  if (denom) {
    ((float4*)orow)[t] = o;
    __syncthreads();
    if (t < NHEADS) {
      float s = 0.0f;
#pragma unroll
      for (int i = 0; i < HEADD; ++i) {
        float v = orow[t * HEADD + i];
        s = fmaf(v, v, s);
      }
      denom[t * N_NODES + row] = fmaxf(1.0f - s, 1e-15f);
    }
  }
}

// ---------- ctxT[h][e][d] = sum_n v2[h,n,d] * (gamma/den * mask * V)[h,n,e]  (v2,V bf16) ----------
__global__ __launch_bounds__(256) void context_kernel(const ushort_t* __restrict__ v2buf,
                                                      const ushort_t* __restrict__ vbuf,
                                                      const float* __restrict__ denom,
                                                      const float* __restrict__ mask,
                                                      float* __restrict__ ctxT) {
  __shared__ float s2[64][65];
  __shared__ float sx[64][65];
  const int h = blockIdx.y;
  const int t = threadIdx.x;
  const int d0 = (t >> 4) * 4;
  const int e0 = (t & 15) * 4;
  float acc[4][4];
#pragma unroll
  for (int i = 0; i < 4; ++i)
#pragma unroll
    for (int j = 0; j < 4; ++j) acc[i][j] = 0.0f;

  const int rbase = blockIdx.x * 512;
  for (int c = 0; c < 8; ++c) {
#pragma unroll
    for (int i = 0; i < 4; ++i) {
      int f = i * 256 + t;
      int r = f >> 4;
      int cc = (f & 15) * 4;
      int row = rbase + c * 64 + r;
      uint2 araw = *(const uint2*)(v2buf + (size_t)row * DIMV + h * HEADD + cc);
      ushort_t* ah = (ushort_t*)&araw;
      s2[r][cc + 0] = b2f(ah[0]); s2[r][cc + 1] = b2f(ah[1]);
      s2[r][cc + 2] = b2f(ah[2]); s2[r][cc + 3] = b2f(ah[3]);
      float dp = denom[(size_t)h * N_NODES + row];
      float gamma = 2.0f / dp;
      float den = clampabs(gamma - 1.0f, 1e-10f);
      float c1 = gamma / den * mask[row];
      uint2 braw = *(const uint2*)(vbuf + (size_t)row * DIMV + h * HEADD + cc);
      ushort_t* bh = (ushort_t*)&braw;
      sx[r][cc + 0] = c1 * b2f(bh[0]); sx[r][cc + 1] = c1 * b2f(bh[1]);
      sx[r][cc + 2] = c1 * b2f(bh[2]); sx[r][cc + 3] = c1 * b2f(bh[3]);
    }
    __syncthreads();
    for (int r = 0; r < 64; ++r) {
      float av[4], bv[4];
#pragma unroll
      for (int i = 0; i < 4; ++i) av[i] = s2[r][d0 + i];
#pragma unroll
      for (int j = 0; j < 4; ++j) bv[j] = sx[r][e0 + j];
#pragma unroll
      for (int i = 0; i < 4; ++i)
#pragma unroll
        for (int j = 0; j < 4; ++j) acc[i][j] = fmaf(av[i], bv[j], acc[i][j]);
    }
    __syncthreads();
  }
#pragma unroll
  for (int i = 0; i < 4; ++i)
#pragma unroll
    for (int j = 0; j < 4; ++j)
      atomicAdd(&ctxT[h * 4096 + (e0 + j) * 64 + (d0 + i)], acc[i][j]);
}

// ---------- out (MFMA): [out|D] = v1 @ [ctx|v2sum]; tail; emit combHi/Lo + rownorm atomics ----------
__global__ __launch_bounds__(256) void out_mfma_kernel(const ushort_t* __restrict__ v1bf,
                                                       const float* __restrict__ v2sum,
                                                       const float* __restrict__ ctxT,
                                                       ushort_t* __restrict__ combHi,
                                                       ushort_t* __restrict__ combLo,
                                                       float* __restrict__ combnorm) {
  __shared__ ushort_t Blds[80][88];
  const int h = blockIdx.y;
  const int bm = blockIdx.x * 256;
  const int t = threadIdx.x;
  const int w = t >> 6, lane = t & 63, l15 = lane & 15;
  const int kk = (lane >> 4) * 8;

  for (int idx = t; idx < 80 * 64; idx += 256) {
    int e = idx >> 6, d = idx & 63;
    float v = 0.0f;
    if (e < 64) v = ctxT[h * 4096 + e * 64 + d];
    else if (e == 64) v = v2sum[h * 64 + d];
    Blds[e][d] = f2b(v);
  }
  __syncthreads();

  f32x4 acc[4][5];
#pragma unroll
  for (int i = 0; i < 4; ++i)
#pragma unroll
    for (int j = 0; j < 5; ++j) acc[i][j] = (f32x4){0.f, 0.f, 0.f, 0.f};
#pragma unroll
  for (int ks = 0; ks < 2; ++ks) {
    short8 bfr[5];
#pragma unroll
    for (int j = 0; j < 5; ++j) bfr[j] = *(const short8*)&Blds[j * 16 + l15][ks * 32 + kk];
#pragma unroll
    for (int i = 0; i < 4; ++i) {
      short8 af = *(const short8*)(v1bf + (size_t)(bm + w * 64 + i * 16 + l15) * DIMV +
                                   h * HEADD + ks * 32 + kk);
#pragma unroll
      for (int j = 0; j < 5; ++j)
        acc[i][j] = __builtin_amdgcn_mfma_f32_16x16x32_bf16(af, bfr[j], acc[i][j], 0, 0, 0);
    }
  }

  const int g4 = (lane >> 4) * 4;
#pragma unroll
  for (int i = 0; i < 4; ++i) {
#pragma unroll
    for (int r = 0; r < 4; ++r) {
      const int row = bm + w * 64 + i * 16 + g4 + r;
      float D = __shfl(acc[i][4][r], lane & 48);
      float Dinv = 1.0f / (D == 0.0f ? 1e-5f : D);
      float o[4];
      float s = 0.0f;
#pragma unroll
      for (int j = 0; j < 4; ++j) {
        o[j] = acc[i][j][r] * Dinv;
        s = fmaf(o[j], o[j], s);
      }
      s += __shfl_xor(s, 1); s += __shfl_xor(s, 2);
      s += __shfl_xor(s, 4); s += __shfl_xor(s, 8);
      float n1 = fmaxf(sqrtf(s), 1e-15f);
      float sc = 1.0f;
      if (n1 > 0.996f) sc = 0.996f / n1;
      float xn = fmaxf(fminf(n1, 0.996f), 1e-15f);
      float cx = fminf(xn, 1.0f - 1e-7f);
      float t2 = tanhf(0.5f * atanhf(cx));
      sc *= t2 / xn;
      if (t2 > 0.996f) sc *= 0.996f / t2;
      if (l15 == 0) atomicAdd(&combnorm[row], s * sc * sc);
#pragma unroll
      for (int j = 0; j < 4; ++j) {
        float ov = o[j] * sc;
        size_t off = (size_t)row * DIMV + h * HEADD + j * 16 + l15;
        ushort_t hi = f2b(ov);
        combHi[off] = hi;
        combLo[off] = f2b(ov - b2f(hi));
      }
    }
  }
}

// ---------- launch ----------

extern "C" void kernel_launch(void* const* d_in, const int* in_sizes, int n_in,
                              void* d_out, int out_size, void* d_ws, size_t ws_size,
                              hipStream_t stream) {
  const float* X = (const float*)d_in[0];
  const float* mask = (const float*)d_in[1];
  const float* Wq = (const float*)d_in[2];
  const float* bq = (const float*)d_in[3];
  const float* Wk = (const float*)d_in[4];
  const float* bk = (const float*)d_in[5];
  const float* Wv = (const float*)d_in[6];
  const float* Wff = (const float*)d_in[7];
  float* out = (float*)d_out;

  const size_t MAT = (size_t)N_NODES * DIMV;
  char* p = (char*)d_ws;
  // R1 (64MB): first half v1bf (QK epi out); second half mxV bf16, later combnorm
  ushort_t* v1bf = (ushort_t*)p;
  ushort_t* mxV = (ushort_t*)(p + MAT * 2);
  float* combnorm = (float*)(p + MAT * 2);
  p += MAT * 4;
  // R2 (64MB): xnormsq (early) / v2bf (QK epi out) / combHi+combLo (after context)
  float* xnormsq = (float*)p;
  ushort_t* v2bf = (ushort_t*)p;
  ushort_t* combHi = (ushort_t*)p;
  ushort_t* combLo = combHi + MAT;
  p += MAT * 4;
  // R3 (32MB): Vbf; later WffHi/WffLo
  ushort_t* Vbf = (ushort_t*)p;
  ushort_t* WffHi = Vbf;
  ushort_t* WffLo = Vbf + (size_t)DIMV * DIMV;
  p += MAT * 2;
  // R4 (32MB): Xbf; later outBf (split3 out)
  ushort_t* Xbf = (ushort_t*)p;
  ushort_t* outBf = Xbf;
  p += MAT * 2;
  float* denom = (float*)p;  p += (size_t)NHEADS * N_NODES * 4;
  float* v2sum = (float*)p;  p += 1024 * 4;
  float* ctxT = (float*)p;   p += (size_t)NHEADS * 4096 * 4;
  const size_t need = (size_t)(p - (char*)d_ws);
  if (ws_size < need) return;

  // W^T bf16 scratch inside d_out (free until the final rowtrans writes it):
  ushort_t* Wt = (ushort_t*)d_out;            // Wv^T, later Wq^T (rows 0..1023)
  ushort_t* WtK = Wt + (size_t)DIMV * DIMV;   // Wk^T (rows 1024..2047 of stacked QK)

  dim3 tgrid(32, 32);

  cvt_norm_kernel<<<N_NODES, 256, 0, stream>>>(X, Xbf, xnormsq);
  // V path: mxV bf16, then rowtrans -> Vbf + denom
  transW_kernel<false><<<tgrid, 256, 0, stream>>>(Wv, Wt, nullptr);
  gemm_bf<0, 4><<<256, 512, 0, stream>>>(Xbf, Wt, nullptr, nullptr, nullptr, nullptr,
                                         nullptr, mxV, nullptr);
  rowtrans_kernel<true><<<N_NODES, 256, 0, stream>>>(mxV, xnormsq, Vbf, denom);
  // zero accumulators (v2sum+ctxT contiguous; combnorm over dead mxV)
  hipMemsetAsync(v2sum, 0, (1024 + 4096 * NHEADS) * sizeof(float), stream);
  hipMemsetAsync(combnorm, 0, N_NODES * sizeof(float), stream);
  // QK fused: stacked [Wq^T; Wk^T], epilogue emits v1 (cols<1024) and v2 + v2sum (cols>=1024)
  transW_kernel<false><<<tgrid, 256, 0, stream>>>(Wq, Wt, nullptr);
  transW_kernel<false><<<tgrid, 256, 0, stream>>>(Wk, WtK, nullptr);
  gemm_bf<3, 8><<<512, 512, 0, stream>>>(Xbf, Wt, bq, bk, denom, mask, v2sum, v1bf, v2bf);
  // context (transposed output)
  context_kernel<<<dim3(32, NHEADS), 256, 0, stream>>>(v2bf, Vbf, denom, mask, ctxT);
  // attention out -> combHi/Lo + row norms
  out_mfma_kernel<<<dim3(N_NODES / 256, NHEADS), 256, 0, stream>>>(v1bf, v2sum, ctxT, combHi,
                                                                   combLo, combnorm);
  // final: fused 3-term split GEMM -> outBf, then rowtrans -> d_out
  transW_kernel<true><<<tgrid, 256, 0, stream>>>(Wff, WffHi, WffLo);
  gemm_split3<<<256, 512, 0, stream>>>(combHi, combLo, WffHi, WffLo, outBf);
  rowtrans_kernel<false><<<N_NODES, 256, 0, stream>>>(outBf, combnorm, out, nullptr);
}

// Round 8
// 513.686 us; speedup vs baseline: 1.0853x; 1.0183x over previous
//
#include <hip/hip_runtime.h>
#include <hip/hip_bf16.h>
#include <math.h>

#define N_NODES 16384
#define DIMV 1024
#define NHEADS 16
#define HEADD 64

typedef __attribute__((ext_vector_type(8))) short short8;
typedef __attribute__((ext_vector_type(4))) float f32x4;
typedef unsigned short ushort_t;

// async global->LDS, 16B per lane; LDS dest is wave-uniform base + lane*16
#define GLD16(gptr, lptr)                                                                 \
  __builtin_amdgcn_global_load_lds((const __attribute__((address_space(1))) void*)(gptr), \
                                   (__attribute__((address_space(3))) void*)(lptr), 16, 0, 0)

// ---------- helpers ----------

__device__ __forceinline__ float waveReduceSum(float v) {
#pragma unroll
  for (int m = 32; m; m >>= 1) v += __shfl_xor(v, m);
  return v;
}

__device__ __forceinline__ float blockReduceSum(float v, float* red) {
  float w = waveReduceSum(v);
  __syncthreads();
  if ((threadIdx.x & 63) == 0) red[threadIdx.x >> 6] = w;
  __syncthreads();
  return red[0] + red[1] + red[2] + red[3];
}

__device__ __forceinline__ float elup1(float z) {
  return z > 0.0f ? z + 1.0f : expm1f(z) + 1.0f;
}

__device__ __forceinline__ float clampabs(float x, float eps) {
  float s = (x >= 0.0f) ? 1.0f : -1.0f;
  return s * fmaxf(fabsf(x), eps);
}

// fp32 -> bf16 bits, RNE
__device__ __forceinline__ ushort_t f2b(float x) {
  unsigned u = __float_as_uint(x);
  unsigned r = (u + 0x7FFFu + ((u >> 16) & 1u)) >> 16;
  return (ushort_t)r;
}
__device__ __forceinline__ float b2f(ushort_t h) {
  return __uint_as_float(((unsigned)h) << 16);
}

// ---------- X -> bf16 + row sumsq (one block per row) ----------
__global__ __launch_bounds__(256) void cvt_norm_kernel(const float* __restrict__ src,
                                                       ushort_t* __restrict__ dst,
                                                       float* __restrict__ rowsq) {
  __shared__ float red[4];
  const int row = blockIdx.x;
  const int t = threadIdx.x;
  float4 x4 = ((const float4*)(src + (size_t)row * DIMV))[t];
  ushort_t h[4] = {f2b(x4.x), f2b(x4.y), f2b(x4.z), f2b(x4.w)};
  ((uint2*)(dst + (size_t)row * DIMV))[t] = *(uint2*)h;
  float s = x4.x * x4.x + x4.y * x4.y + x4.z * x4.z + x4.w * x4.w;
  s = blockReduceSum(s, red);
  if (t == 0) rowsq[row] = s;
}

// ---------- weight transpose -> bf16 (hi, and optional lo residual) ----------
template <bool LO>
__global__ __launch_bounds__(256) void transW_kernel(const float* __restrict__ src,
                                                     ushort_t* __restrict__ hi,
                                                     ushort_t* __restrict__ lo) {
  __shared__ float tile[32][33];
  const int bx = blockIdx.x * 32, by = blockIdx.y * 32;
  const int tx = threadIdx.x & 31, ty = threadIdx.x >> 5;
#pragma unroll
  for (int i = 0; i < 32; i += 8) tile[ty + i][tx] = src[(size_t)(by + ty + i) * DIMV + bx + tx];
  __syncthreads();
#pragma unroll
  for (int i = 0; i < 32; i += 8) {
    float v = tile[tx][ty + i];
    ushort_t h = f2b(v);
    hi[(size_t)(bx + ty + i) * DIMV + by + tx] = h;
    if (LO) lo[(size_t)(bx + ty + i) * DIMV + by + tx] = f2b(v - b2f(h));
  }
}

// k-unit swizzle (16B units within a 64B row): LDS[row][u] holds global unit u ^ ((row>>1)&3).
// Source side: lane loads global unit (lane&3)^((lane>>3)&3) (row = lane>>2 within chunk).
// Read side: kk-unit (lane>>4) at row (..+l15) lives at unit (lane>>4)^((lane>>1)&3).
// Result: 2 lanes/bank on ds_read_b128 (free) instead of 8-16-way conflicts.

// ---------- bf16 MFMA GEMM, 256x256 tile, BK=32, 8 waves, dbuf, swizzled LDS ----------
// A: [M][1024] bf16, Bt: [NB*256 n][1024 k] bf16. Per wave: 128x64 out = acc[8][4].
// EPI 0: Cq = bf16(acc)                                  (V path)
// EPI 3: cols < 1024 -> Cq = bf16(v1); cols >= 1024 -> Ck = bf16(v2), v2sum atomics (QK fused)
// Epilogue: LDS-transposed coalesced stores (two 128-row passes).
template <int EPI, int NB>
__global__ __launch_bounds__(512, 2) void gemm_bf(const ushort_t* __restrict__ A,
                                                  const ushort_t* __restrict__ Bt,
                                                  const float* __restrict__ biasQ,
                                                  const float* __restrict__ biasK,
                                                  const float* __restrict__ denom,
                                                  const float* __restrict__ mask,
                                                  float* __restrict__ v2sum,
                                                  ushort_t* __restrict__ Cq,
                                                  ushort_t* __restrict__ Ck) {
  __shared__ ushort_t LB[32768];  // 64 KB: A at [buf*8192], B at [16384 + buf*8192]
  const int bid = blockIdx.x;
  const int nwg = NB * 64;
  const int swz = (bid & 7) * (nwg / 8) + (bid >> 3);
  const int bm = (swz / NB) * 256;
  const int bn = (swz % NB) * 256;
  const int t = threadIdx.x;
  const int w = t >> 6, lane = t & 63, l15 = lane & 15;
  const int wr = (w >> 2) * 128;
  const int wcn = (w & 3) * 64;
  const int kks = (((lane >> 4) ^ ((lane >> 1) & 3)) << 3);  // swizzled k-offset (elements)
  const int sksw = (((lane & 3) ^ ((lane >> 3) & 3)) << 3);  // staging src k-offset

  // staging: chunks of 16 rows x 64B; wave w takes chunks w and w+8 per operand.
  const ushort_t *gA[2], *gB[2];
  int lofs[2];
#pragma unroll
  for (int c = 0; c < 2; ++c) {
    const int ch = w + 8 * c;
    lofs[c] = ch * 512 + lane * 8;
    gA[c] = A + (size_t)(bm + ch * 16 + (lane >> 2)) * DIMV + sksw;
    gB[c] = Bt + (size_t)(bn + ch * 16 + (lane >> 2)) * DIMV + sksw;
  }

#define STAGE_G(buf, k0)                              \
  do {                                                \
    _Pragma("unroll") for (int c = 0; c < 2; ++c) {   \
      GLD16(gA[c] + (k0), &LB[(buf)*8192 + lofs[c]]); \
      GLD16(gB[c] + (k0), &LB[16384 + (buf)*8192 + lofs[c]]); \
    }                                                 \
  } while (0)

  f32x4 acc[8][4];
#pragma unroll
  for (int i = 0; i < 8; ++i)
#pragma unroll
    for (int j = 0; j < 4; ++j) acc[i][j] = (f32x4){0.f, 0.f, 0.f, 0.f};

  STAGE_G(0, 0);
  __syncthreads();
  int cur = 0;
  for (int k0 = 0; k0 < DIMV; k0 += 32) {
    if (k0 + 32 < DIMV) STAGE_G(cur ^ 1, k0 + 32);
    short8 bf[4];
#pragma unroll
    for (int j = 0; j < 4; ++j)
      bf[j] = *(const short8*)&LB[16384 + cur * 8192 + (wcn + j * 16 + l15) * 32 + kks];
#pragma unroll
    for (int i = 0; i < 8; ++i) {
      short8 af = *(const short8*)&LB[cur * 8192 + (wr + i * 16 + l15) * 32 + kks];
#pragma unroll
      for (int j = 0; j < 4; ++j)
        acc[i][j] = __builtin_amdgcn_mfma_f32_16x16x32_bf16(af, bf[j], acc[i][j], 0, 0, 0);
    }
    __syncthreads();
    cur ^= 1;
  }
#undef STAGE_G

  // ---- epilogue: math -> LDS [128][256] bf16 -> coalesced global stores, 2 passes ----
  const int rbase = (lane >> 4) * 4;
  const int prow = w >> 2;  // which 128-row half this wave owns
  const bool isK = (EPI == 3) && (bn >= DIMV);
  const int h = ((bn + wcn) >> 6) & (NHEADS - 1);
  ushort_t* dst = (EPI == 3 && isK) ? Ck : Cq;
  const int coloff = (EPI == 3) ? (bn & (DIMV - 1)) : bn;
  float bb[4];
#pragma unroll
  for (int j = 0; j < 4; ++j)
    bb[j] = (EPI == 3) ? (isK ? biasK[(bn + wcn + j * 16 + l15) & (DIMV - 1)]
                              : biasQ[(bn + wcn + j * 16 + l15) & (DIMV - 1)])
                       : 0.0f;
  float csum[4] = {0.f, 0.f, 0.f, 0.f};

#pragma unroll
  for (int p = 0; p < 2; ++p) {
    if (prow == p) {
#pragma unroll
      for (int i = 0; i < 8; ++i) {
#pragma unroll
        for (int r = 0; r < 4; ++r) {
          const int row_l = i * 16 + rbase + r;
          float invdp = 1.0f, den = 0.f, mk = 0.f;
          if (EPI == 3) {
            invdp = 1.0f / denom[(size_t)h * N_NODES + bm + p * 128 + row_l];
            if (isK) {
              den = clampabs(2.0f * invdp - 1.0f, 1e-10f);
              mk = mask[bm + p * 128 + row_l];
            }
          }
#pragma unroll
          for (int j = 0; j < 4; ++j) {
            float val = acc[i][j][r];
            if (EPI == 3) {
              val = elup1((val + bb[j]) * invdp);
              if (isK) {
                val = den * val * mk;
                csum[j] += val;
              }
            }
            LB[row_l * 256 + wcn + j * 16 + l15] = f2b(val);
          }
        }
      }
    }
    __syncthreads();
#pragma unroll
    for (int it = 0; it < 8; ++it) {
      const int idx = it * 512 + t;
      const int row_l = idx >> 5, cq = idx & 31;
      uint4 v = *(const uint4*)&LB[row_l * 256 + cq * 8];
      *(uint4*)(dst + (size_t)(bm + p * 128 + row_l) * DIMV + coloff + cq * 8) = v;
    }
    __syncthreads();
  }
  if (EPI == 3 && isK) {
#pragma unroll
    for (int j = 0; j < 4; ++j)
      atomicAdd(&v2sum[(bn + wcn + j * 16 + l15) & (DIMV - 1)], csum[j]);
  }
}

// ---------- fused 3-term split GEMM: C = bf16(AhiBhi + AloBhi + AhiBlo) ----------
// 256x256 tile, BK=32, 8 waves, dbuf, swizzled LDS, coalesced epilogue. 128 KB LDS.
__global__ __launch_bounds__(512, 2) void gemm_split3(const ushort_t* __restrict__ Ahi,
                                                      const ushort_t* __restrict__ Alo,
                                                      const ushort_t* __restrict__ Bhi,
                                                      const ushort_t* __restrict__ Blo,
                                                      ushort_t* __restrict__ C) {
  __shared__ ushort_t LB[65536];  // AH:0 AL:16384 BH:32768 BL:49152, each [2][8192]
  const int bid = blockIdx.x;
  const int swz = (bid & 7) * 32 + (bid >> 3);  // nwg = 256
  const int bm = (swz >> 2) * 256;
  const int bn = (swz & 3) * 256;
  const int t = threadIdx.x;
  const int w = t >> 6, lane = t & 63, l15 = lane & 15;
  const int wr = (w >> 2) * 128;
  const int wcn = (w & 3) * 64;
  const int kks = (((lane >> 4) ^ ((lane >> 1) & 3)) << 3);
  const int sksw = (((lane & 3) ^ ((lane >> 3) & 3)) << 3);

  size_t goA[2], goB[2];
  int lofs[2];
#pragma unroll
  for (int c = 0; c < 2; ++c) {
    const int ch = w + 8 * c;
    lofs[c] = ch * 512 + lane * 8;
    goA[c] = (size_t)(bm + ch * 16 + (lane >> 2)) * DIMV + sksw;
    goB[c] = (size_t)(bn + ch * 16 + (lane >> 2)) * DIMV + sksw;
  }

#define STAGE_S(buf, k0)                                          \
  do {                                                            \
    _Pragma("unroll") for (int c = 0; c < 2; ++c) {               \
      GLD16(Ahi + goA[c] + (k0), &LB[(buf)*8192 + lofs[c]]);      \
      GLD16(Alo + goA[c] + (k0), &LB[16384 + (buf)*8192 + lofs[c]]); \
      GLD16(Bhi + goB[c] + (k0), &LB[32768 + (buf)*8192 + lofs[c]]); \
      GLD16(Blo + goB[c] + (k0), &LB[49152 + (buf)*8192 + lofs[c]]); \
    }                                                             \
  } while (0)

  f32x4 acc[8][4];
#pragma unroll
  for (int i = 0; i < 8; ++i)
#pragma unroll
    for (int j = 0; j < 4; ++j) acc[i][j] = (f32x4){0.f, 0.f, 0.f, 0.f};

  STAGE_S(0, 0);
  __syncthreads();
  int cur = 0;
  for (int k0 = 0; k0 < DIMV; k0 += 32) {
    if (k0 + 32 < DIMV) STAGE_S(cur ^ 1, k0 + 32);
    short8 bfH[4], bfL[4];
#pragma unroll
    for (int j = 0; j < 4; ++j) {
      bfH[j] = *(const short8*)&LB[32768 + cur * 8192 + (wcn + j * 16 + l15) * 32 + kks];
      bfL[j] = *(const short8*)&LB[49152 + cur * 8192 + (wcn + j * 16 + l15) * 32 + kks];
    }
#pragma unroll
    for (int i = 0; i < 8; ++i) {
      short8 afH = *(const short8*)&LB[cur * 8192 + (wr + i * 16 + l15) * 32 + kks];
      short8 afL = *(const short8*)&LB[16384 + cur * 8192 + (wr + i * 16 + l15) * 32 + kks];
#pragma unroll
      for (int j = 0; j < 4; ++j) {
        acc[i][j] = __builtin_amdgcn_mfma_f32_16x16x32_bf16(afH, bfH[j], acc[i][j], 0, 0, 0);
        acc[i][j] = __builtin_amdgcn_mfma_f32_16x16x32_bf16(afL, bfH[j], acc[i][j], 0, 0, 0);
        acc[i][j] = __builtin_amdgcn_mfma_f32_16x16x32_bf16(afH, bfL[j], acc[i][j], 0, 0, 0);
      }
    }
    __syncthreads();
    cur ^= 1;
  }
#undef STAGE_S

  // coalesced epilogue via LDS [128][256] (reuses first 64KB)
  const int rbase = (lane >> 4) * 4;
  const int prow = w >> 2;
#pragma unroll
  for (int p = 0; p < 2; ++p) {
    if (prow == p) {
#pragma unroll
      for (int i = 0; i < 8; ++i)
#pragma unroll
        for (int r = 0; r < 4; ++r) {
          const int row_l = i * 16 + rbase + r;
#pragma unroll
          for (int j = 0; j < 4; ++j)
            LB[row_l * 256 + wcn + j * 16 + l15] = f2b(acc[i][j][r]);
        }
    }
    __syncthreads();
#pragma unroll
    for (int it = 0; it < 8; ++it) {
      const int idx = it * 512 + t;
      const int row_l = idx >> 5, cq = idx & 31;
      uint4 v = *(const uint4*)&LB[row_l * 256 + cq * 8];
      *(uint4*)(C + (size_t)(bm + p * 128 + row_l) * DIMV + bn + cq * 8) = v;
    }
    __syncthreads();
  }
}

// ---------- row transform: mobius_matvec tail + kappa_relu (bf16 msrc, precomputed ||x||^2) ----------
template <bool BFDST>
__global__ __launch_bounds__(256) void rowtrans_kernel(const ushort_t* __restrict__ msrc,
                                                       const float* __restrict__ rowsq,
                                                       void* __restrict__ dstv,
                                                       float* __restrict__ denom) {
  __shared__ float red[4];
  __shared__ float orow[DIMV];
  const int row = blockIdx.x;
  const int t = threadIdx.x;
  uint2 mraw = ((const uint2*)(msrc + (size_t)row * DIMV))[t];
  ushort_t* mh = (ushort_t*)&mraw;
  float4 m4 = make_float4(b2f(mh[0]), b2f(mh[1]), b2f(mh[2]), b2f(mh[3]));
  float sm = m4.x * m4.x + m4.y * m4.y + m4.z * m4.z + m4.w * m4.w;
  sm = blockReduceSum(sm, red);
  float sx = rowsq[row];

  float xn = fmaxf(sqrtf(sx), 1e-15f);
  float mxn = fmaxf(sqrtf(sm), 1e-15f);
  float cx = fminf(xn, 1.0f - 1e-7f);
  float t1 = tanhf(mxn / xn * atanhf(cx));
  float s1 = t1 / mxn;

  float yn = fmaxf(fabsf(t1), 1e-15f);
  float a = atanhf(fminf(yn, 1.0f - 1e-7f)) / yn;
  float k1 = a * s1;
  float4 u = make_float4(fmaxf(k1 * m4.x, 0.0f), fmaxf(k1 * m4.y, 0.0f),
                         fmaxf(k1 * m4.z, 0.0f), fmaxf(k1 * m4.w, 0.0f));
  float su = u.x * u.x + u.y * u.y + u.z * u.z + u.w * u.w;
  su = blockReduceSum(su, red);

  float un = fmaxf(sqrtf(su), 1e-15f);
  float t2 = tanhf(un);
  float s2 = t2 / un;
  if (t2 > 0.996f) s2 *= 0.996f / t2;
  float4 o = make_float4(s2 * u.x, s2 * u.y, s2 * u.z, s2 * u.w);
  if (BFDST) {
    ushort_t h[4] = {f2b(o.x), f2b(o.y), f2b(o.z), f2b(o.w)};
    ((uint2*)((ushort_t*)dstv + (size_t)row * DIMV))[t] = *(uint2*)h;
  } else {
    ((float4*)((float*)dstv + (size_t)row * DIMV))[t] = o;
  }

  if (denom) {
    ((float4*)orow)[t] = o;
    __syncthreads();
    if (t < NHEADS) {
      float s = 0.0f;
#pragma unroll
      for (int i = 0; i < HEADD; ++i) {
        float v = orow[t * HEADD + i];
        s = fmaf(v, v, s);
      }
      denom[t * N_NODES + row] = fmaxf(1.0f - s, 1e-15f);
    }
  }
}

// ---------- ctxT[h][e][d] = sum_n v2[h,n,d] * (gamma/den * mask * V)[h,n,e]  (v2,V bf16) ----------
__global__ __launch_bounds__(256) void context_kernel(const ushort_t* __restrict__ v2buf,
                                                      const ushort_t* __restrict__ vbuf,
                                                      const float* __restrict__ denom,
                                                      const float* __restrict__ mask,
                                                      float* __restrict__ ctxT) {
  __shared__ float s2[64][65];
  __shared__ float sx[64][65];
  const int h = blockIdx.y;
  const int t = threadIdx.x;
  const int d0 = (t >> 4) * 4;
  const int e0 = (t & 15) * 4;
  float acc[4][4];
#pragma unroll
  for (int i = 0; i < 4; ++i)
#pragma unroll
    for (int j = 0; j < 4; ++j) acc[i][j] = 0.0f;

  const int rbase = blockIdx.x * 512;
  for (int c = 0; c < 8; ++c) {
#pragma unroll
    for (int i = 0; i < 4; ++i) {
      int f = i * 256 + t;
      int r = f >> 4;
      int cc = (f & 15) * 4;
      int row = rbase + c * 64 + r;
      uint2 araw = *(const uint2*)(v2buf + (size_t)row * DIMV + h * HEADD + cc);
      ushort_t* ah = (ushort_t*)&araw;
      s2[r][cc + 0] = b2f(ah[0]); s2[r][cc + 1] = b2f(ah[1]);
      s2[r][cc + 2] = b2f(ah[2]); s2[r][cc + 3] = b2f(ah[3]);
      float dp = denom[(size_t)h * N_NODES + row];
      float gamma = 2.0f / dp;
      float den = clampabs(gamma - 1.0f, 1e-10f);
      float c1 = gamma / den * mask[row];
      uint2 braw = *(const uint2*)(vbuf + (size_t)row * DIMV + h * HEADD + cc);
      ushort_t* bh = (ushort_t*)&braw;
      sx[r][cc + 0] = c1 * b2f(bh[0]); sx[r][cc + 1] = c1 * b2f(bh[1]);
      sx[r][cc + 2] = c1 * b2f(bh[2]); sx[r][cc + 3] = c1 * b2f(bh[3]);
    }
    __syncthreads();
    for (int r = 0; r < 64; ++r) {
      float av[4], bv[4];
#pragma unroll
      for (int i = 0; i < 4; ++i) av[i] = s2[r][d0 + i];
#pragma unroll
      for (int j = 0; j < 4; ++j) bv[j] = sx[r][e0 + j];
#pragma unroll
      for (int i = 0; i < 4; ++i)
#pragma unroll
        for (int j = 0; j < 4; ++j) acc[i][j] = fmaf(av[i], bv[j], acc[i][j]);
    }
    __syncthreads();
  }
#pragma unroll
  for (int i = 0; i < 4; ++i)
#pragma unroll
    for (int j = 0; j < 4; ++j)
      atomicAdd(&ctxT[h * 4096 + (e0 + j) * 64 + (d0 + i)], acc[i][j]);
}

// ---------- out (MFMA): [out|D] = v1 @ [ctx|v2sum]; tail; emit combHi/Lo + rownorm atomics ----------
__global__ __launch_bounds__(256) void out_mfma_kernel(const ushort_t* __restrict__ v1bf,
                                                       const float* __restrict__ v2sum,
                                                       const float* __restrict__ ctxT,
                                                       ushort_t* __restrict__ combHi,
                                                       ushort_t* __restrict__ combLo,
                                                       float* __restrict__ combnorm) {
  __shared__ ushort_t Blds[80][88];
  const int h = blockIdx.y;
  const int bm = blockIdx.x * 256;
  const int t = threadIdx.x;
  const int w = t >> 6, lane = t & 63, l15 = lane & 15;
  const int kk = (lane >> 4) * 8;

  for (int idx = t; idx < 80 * 64; idx += 256) {
    int e = idx >> 6, d = idx & 63;
    float v = 0.0f;
    if (e < 64) v = ctxT[h * 4096 + e * 64 + d];
    else if (e == 64) v = v2sum[h * 64 + d];
    Blds[e][d] = f2b(v);
  }
  __syncthreads();

  f32x4 acc[4][5];
#pragma unroll
  for (int i = 0; i < 4; ++i)
#pragma unroll
    for (int j = 0; j < 5; ++j) acc[i][j] = (f32x4){0.f, 0.f, 0.f, 0.f};
#pragma unroll
  for (int ks = 0; ks < 2; ++ks) {
    short8 bfr[5];
#pragma unroll
    for (int j = 0; j < 5; ++j) bfr[j] = *(const short8*)&Blds[j * 16 + l15][ks * 32 + kk];
#pragma unroll
    for (int i = 0; i < 4; ++i) {
      short8 af = *(const short8*)(v1bf + (size_t)(bm + w * 64 + i * 16 + l15) * DIMV +
                                   h * HEADD + ks * 32 + kk);
#pragma unroll
      for (int j = 0; j < 5; ++j)
        acc[i][j] = __builtin_amdgcn_mfma_f32_16x16x32_bf16(af, bfr[j], acc[i][j], 0, 0, 0);
    }
  }

  const int g4 = (lane >> 4) * 4;
#pragma unroll
  for (int i = 0; i < 4; ++i) {
#pragma unroll
    for (int r = 0; r < 4; ++r) {
      const int row = bm + w * 64 + i * 16 + g4 + r;
      float D = __shfl(acc[i][4][r], lane & 48);
      float Dinv = 1.0f / (D == 0.0f ? 1e-5f : D);
      float o[4];
      float s = 0.0f;
#pragma unroll
      for (int j = 0; j < 4; ++j) {
        o[j] = acc[i][j][r] * Dinv;
        s = fmaf(o[j], o[j], s);
      }
      s += __shfl_xor(s, 1); s += __shfl_xor(s, 2);
      s += __shfl_xor(s, 4); s += __shfl_xor(s, 8);
      float n1 = fmaxf(sqrtf(s), 1e-15f);
      float sc = 1.0f;
      if (n1 > 0.996f) sc = 0.996f / n1;
      float xn = fmaxf(fminf(n1, 0.996f), 1e-15f);
      float cx = fminf(xn, 1.0f - 1e-7f);
      float t2 = tanhf(0.5f * atanhf(cx));
      sc *= t2 / xn;
      if (t2 > 0.996f) sc *= 0.996f / t2;
      if (l15 == 0) atomicAdd(&combnorm[row], s * sc * sc);
#pragma unroll
      for (int j = 0; j < 4; ++j) {
        float ov = o[j] * sc;
        size_t off = (size_t)row * DIMV + h * HEADD + j * 16 + l15;
        ushort_t hi = f2b(ov);
        combHi[off] = hi;
        combLo[off] = f2b(ov - b2f(hi));
      }
    }
  }
}

// ---------- launch ----------

extern "C" void kernel_launch(void* const* d_in, const int* in_sizes, int n_in,
                              void* d_out, int out_size, void* d_ws, size_t ws_size,
                              hipStream_t stream) {
  const float* X = (const float*)d_in[0];
  const float* mask = (const float*)d_in[1];
  const float* Wq = (const float*)d_in[2];
  const float* bq = (const float*)d_in[3];
  const float* Wk = (const float*)d_in[4];
  const float* bk = (const float*)d_in[5];
  const float* Wv = (const float*)d_in[6];
  const float* Wff = (const float*)d_in[7];
  float* out = (float*)d_out;

  const size_t MAT = (size_t)N_NODES * DIMV;
  char* p = (char*)d_ws;
  // R1 (64MB): first half v1bf (QK epi out); second half mxV bf16, later combnorm
  ushort_t* v1bf = (ushort_t*)p;
  ushort_t* mxV = (ushort_t*)(p + MAT * 2);
  float* combnorm = (float*)(p + MAT * 2);
  p += MAT * 4;
  // R2 (64MB): xnormsq (early) / v2bf (QK epi out) / combHi+combLo (after context)
  float* xnormsq = (float*)p;
  ushort_t* v2bf = (ushort_t*)p;
  ushort_t* combHi = (ushort_t*)p;
  ushort_t* combLo = combHi + MAT;
  p += MAT * 4;
  // R3 (32MB): Vbf; later WffHi/WffLo
  ushort_t* Vbf = (ushort_t*)p;
  ushort_t* WffHi = Vbf;
  ushort_t* WffLo = Vbf + (size_t)DIMV * DIMV;
  p += MAT * 2;
  // R4 (32MB): Xbf; later outBf (split3 out)
  ushort_t* Xbf = (ushort_t*)p;
  ushort_t* outBf = Xbf;
  p += MAT * 2;
  float* denom = (float*)p;  p += (size_t)NHEADS * N_NODES * 4;
  float* v2sum = (float*)p;  p += 1024 * 4;
  float* ctxT = (float*)p;   p += (size_t)NHEADS * 4096 * 4;
  const size_t need = (size_t)(p - (char*)d_ws);
  if (ws_size < need) return;

  // W^T bf16 scratch inside d_out (free until the final rowtrans writes it):
  ushort_t* Wt = (ushort_t*)d_out;            // Wv^T, later Wq^T (rows 0..1023)
  ushort_t* WtK = Wt + (size_t)DIMV * DIMV;   // Wk^T (rows 1024..2047 of stacked QK)

  dim3 tgrid(32, 32);

  cvt_norm_kernel<<<N_NODES, 256, 0, stream>>>(X, Xbf, xnormsq);
  // V path: mxV bf16, then rowtrans -> Vbf + denom
  transW_kernel<false><<<tgrid, 256, 0, stream>>>(Wv, Wt, nullptr);
  gemm_bf<0, 4><<<256, 512, 0, stream>>>(Xbf, Wt, nullptr, nullptr, nullptr, nullptr,
                                         nullptr, mxV, nullptr);
  rowtrans_kernel<true><<<N_NODES, 256, 0, stream>>>(mxV, xnormsq, Vbf, denom);
  // zero accumulators (v2sum+ctxT contiguous; combnorm over dead mxV)
  hipMemsetAsync(v2sum, 0, (1024 + 4096 * NHEADS) * sizeof(float), stream);
  hipMemsetAsync(combnorm, 0, N_NODES * sizeof(float), stream);
  // QK fused: stacked [Wq^T; Wk^T], epilogue emits v1 (cols<1024) and v2 + v2sum (cols>=1024)
  transW_kernel<false><<<tgrid, 256, 0, stream>>>(Wq, Wt, nullptr);
  transW_kernel<false><<<tgrid, 256, 0, stream>>>(Wk, WtK, nullptr);
  gemm_bf<3, 8><<<512, 512, 0, stream>>>(Xbf, Wt, bq, bk, denom, mask, v2sum, v1bf, v2bf);
  // context (transposed output)
  context_kernel<<<dim3(32, NHEADS), 256, 0, stream>>>(v2bf, Vbf, denom, mask, ctxT);
  // attention out -> combHi/Lo + row norms
  out_mfma_kernel<<<dim3(N_NODES / 256, NHEADS), 256, 0, stream>>>(v1bf, v2sum, ctxT, combHi,
                                                                   combLo, combnorm);
  // final: fused 3-term split GEMM -> outBf, then rowtrans -> d_out
  transW_kernel<true><<<tgrid, 256, 0, stream>>>(Wff, WffHi, WffLo);
  gemm_split3<<<256, 512, 0, stream>>>(combHi, combLo, WffHi, WffLo, outBf);
  rowtrans_kernel<false><<<N_NODES, 256, 0, stream>>>(outBf, combnorm, out, nullptr);
}

// Round 9
// 511.665 us; speedup vs baseline: 1.0896x; 1.0039x over previous
//
#include <hip/hip_runtime.h>
#include <hip/hip_bf16.h>
#include <math.h>

#define N_NODES 16384
#define DIMV 1024
#define NHEADS 16
#define HEADD 64

typedef __attribute__((ext_vector_type(8))) short short8;
typedef __attribute__((ext_vector_type(4))) float f32x4;
typedef unsigned short ushort_t;

// async global->LDS, 16B per lane; LDS dest is wave-uniform base + lane*16
#define GLD16(gptr, lptr)                                                                 \
  __builtin_amdgcn_global_load_lds((const __attribute__((address_space(1))) void*)(gptr), \
                                   (__attribute__((address_space(3))) void*)(lptr), 16, 0, 0)

#define SCHED0() __builtin_amdgcn_sched_barrier(0)
#define SBAR() __builtin_amdgcn_s_barrier()

// ---------- helpers ----------

__device__ __forceinline__ float waveReduceSum(float v) {
#pragma unroll
  for (int m = 32; m; m >>= 1) v += __shfl_xor(v, m);
  return v;
}

__device__ __forceinline__ float blockReduceSum(float v, float* red) {
  float w = waveReduceSum(v);
  __syncthreads();
  if ((threadIdx.x & 63) == 0) red[threadIdx.x >> 6] = w;
  __syncthreads();
  return red[0] + red[1] + red[2] + red[3];
}

__device__ __forceinline__ float elup1(float z) {
  return z > 0.0f ? z + 1.0f : expm1f(z) + 1.0f;
}

__device__ __forceinline__ float clampabs(float x, float eps) {
  float s = (x >= 0.0f) ? 1.0f : -1.0f;
  return s * fmaxf(fabsf(x), eps);
}

// fp32 -> bf16 bits, RNE
__device__ __forceinline__ ushort_t f2b(float x) {
  unsigned u = __float_as_uint(x);
  unsigned r = (u + 0x7FFFu + ((u >> 16) & 1u)) >> 16;
  return (ushort_t)r;
}
__device__ __forceinline__ float b2f(ushort_t h) {
  return __uint_as_float(((unsigned)h) << 16);
}

// ---------- X -> bf16 + row sumsq (one block per row) ----------
__global__ __launch_bounds__(256) void cvt_norm_kernel(const float* __restrict__ src,
                                                       ushort_t* __restrict__ dst,
                                                       float* __restrict__ rowsq) {
  __shared__ float red[4];
  const int row = blockIdx.x;
  const int t = threadIdx.x;
  float4 x4 = ((const float4*)(src + (size_t)row * DIMV))[t];
  ushort_t h[4] = {f2b(x4.x), f2b(x4.y), f2b(x4.z), f2b(x4.w)};
  ((uint2*)(dst + (size_t)row * DIMV))[t] = *(uint2*)h;
  float s = x4.x * x4.x + x4.y * x4.y + x4.z * x4.z + x4.w * x4.w;
  s = blockReduceSum(s, red);
  if (t == 0) rowsq[row] = s;
}

// ---------- weight transpose -> bf16 (hi, and optional lo residual) ----------
template <bool LO>
__global__ __launch_bounds__(256) void transW_kernel(const float* __restrict__ src,
                                                     ushort_t* __restrict__ hi,
                                                     ushort_t* __restrict__ lo) {
  __shared__ float tile[32][33];
  const int bx = blockIdx.x * 32, by = blockIdx.y * 32;
  const int tx = threadIdx.x & 31, ty = threadIdx.x >> 5;
#pragma unroll
  for (int i = 0; i < 32; i += 8) tile[ty + i][tx] = src[(size_t)(by + ty + i) * DIMV + bx + tx];
  __syncthreads();
#pragma unroll
  for (int i = 0; i < 32; i += 8) {
    float v = tile[tx][ty + i];
    ushort_t h = f2b(v);
    hi[(size_t)(bx + ty + i) * DIMV + by + tx] = h;
    if (LO) lo[(size_t)(bx + ty + i) * DIMV + by + tx] = f2b(v - b2f(h));
  }
}

// k-unit swizzle (16B units within a 64B row): LDS[row][u] holds global unit u ^ ((row>>1)&3).
// Source side: lane loads global unit (lane&3)^((lane>>3)&3) (row = lane>>2 within chunk).
// Read side: unit (lane>>4) at row (..+l15) lives at unit (lane>>4)^((lane>>1)&3).

// ---------- bf16 MFMA GEMM, 256x256, BK=32, 8 waves, TRI-buffer counted-vmcnt pipeline ----
// T4: 2-deep prefetch; s_waitcnt vmcnt(4) + raw s_barrier per K-step (never drains the
// newest stage). Stage(kt+2) has ~2 compute phases to land. LDS 96 KB.
// EPI 0: Cq = bf16(acc)                                  (V path)
// EPI 3: cols < 1024 -> Cq = bf16(v1); cols >= 1024 -> Ck = bf16(v2), v2sum atomics (QK fused)
template <int EPI, int NB>
__global__ __launch_bounds__(512, 2) void gemm_bf(const ushort_t* __restrict__ A,
                                                  const ushort_t* __restrict__ Bt,
                                                  const float* __restrict__ biasQ,
                                                  const float* __restrict__ biasK,
                                                  const float* __restrict__ denom,
                                                  const float* __restrict__ mask,
                                                  float* __restrict__ v2sum,
                                                  ushort_t* __restrict__ Cq,
                                                  ushort_t* __restrict__ Ck) {
  __shared__ ushort_t LB[49152];  // 96 KB: A bufs at b*8192, B bufs at 24576 + b*8192
  const int bid = blockIdx.x;
  const int nwg = NB * 64;
  const int swz = (bid & 7) * (nwg / 8) + (bid >> 3);
  const int bm = (swz / NB) * 256;
  const int bn = (swz % NB) * 256;
  const int t = threadIdx.x;
  const int w = t >> 6, lane = t & 63, l15 = lane & 15;
  const int wr = (w >> 2) * 128;
  const int wcn = (w & 3) * 64;
  const int kks = (((lane >> 4) ^ ((lane >> 1) & 3)) << 3);  // swizzled k-offset (elements)
  const int sksw = (((lane & 3) ^ ((lane >> 3) & 3)) << 3);  // staging src k-offset

  // staging: chunks of 16 rows x 64B; wave w takes chunks w and w+8 per operand (4 GLD total).
  const ushort_t *gA[2], *gB[2];
  int lofs[2];
#pragma unroll
  for (int c = 0; c < 2; ++c) {
    const int ch = w + 8 * c;
    lofs[c] = ch * 512 + lane * 8;
    gA[c] = A + (size_t)(bm + ch * 16 + (lane >> 2)) * DIMV + sksw;
    gB[c] = Bt + (size_t)(bn + ch * 16 + (lane >> 2)) * DIMV + sksw;
  }

#define STAGE_G(buf, k0)                                        \
  do {                                                          \
    _Pragma("unroll") for (int c = 0; c < 2; ++c) {             \
      GLD16(gA[c] + (k0), &LB[(buf) * 8192 + lofs[c]]);         \
      GLD16(gB[c] + (k0), &LB[24576 + (buf) * 8192 + lofs[c]]); \
    }                                                           \
  } while (0)

  f32x4 acc[8][4];
#pragma unroll
  for (int i = 0; i < 8; ++i)
#pragma unroll
    for (int j = 0; j < 4; ++j) acc[i][j] = (f32x4){0.f, 0.f, 0.f, 0.f};

  // prologue: 2 stages in flight, wait only for the first
  STAGE_G(0, 0);
  STAGE_G(1, 32);
  SCHED0();
  asm volatile("s_waitcnt vmcnt(4)" ::: "memory");
  SBAR();
  SCHED0();

  int bc = 0, bs = 2;  // compute buf, stage buf = (kt+2)%3
  for (int kt = 0; kt < 32; ++kt) {
    if (kt < 30) STAGE_G(bs, (kt + 2) * 32);
    const int aoff = bc * 8192;
    const int boff = 24576 + bc * 8192;
    short8 bf[4];
#pragma unroll
    for (int j = 0; j < 4; ++j)
      bf[j] = *(const short8*)&LB[boff + (wcn + j * 16 + l15) * 32 + kks];
#pragma unroll
    for (int i = 0; i < 8; ++i) {
      short8 af = *(const short8*)&LB[aoff + (wr + i * 16 + l15) * 32 + kks];
#pragma unroll
      for (int j = 0; j < 4; ++j)
        acc[i][j] = __builtin_amdgcn_mfma_f32_16x16x32_bf16(af, bf[j], acc[i][j], 0, 0, 0);
    }
    SCHED0();
    if (kt < 30)
      asm volatile("s_waitcnt vmcnt(4)" ::: "memory");  // older stage retired; newest flies on
    else
      asm volatile("s_waitcnt vmcnt(0)" ::: "memory");  // tail drain
    SBAR();
    SCHED0();
    bc = (bc == 2) ? 0 : bc + 1;
    bs = (bs == 2) ? 0 : bs + 1;
  }
#undef STAGE_G

  // ---- epilogue: math -> LDS [128][256] bf16 -> coalesced global stores, 2 passes ----
  const int rbase = (lane >> 4) * 4;
  const int prow = w >> 2;  // which 128-row half this wave owns
  const bool isK = (EPI == 3) && (bn >= DIMV);
  const int h = ((bn + wcn) >> 6) & (NHEADS - 1);
  ushort_t* dst = (EPI == 3 && isK) ? Ck : Cq;
  const int coloff = (EPI == 3) ? (bn & (DIMV - 1)) : bn;
  float bb[4];
#pragma unroll
  for (int j = 0; j < 4; ++j)
    bb[j] = (EPI == 3) ? (isK ? biasK[(bn + wcn + j * 16 + l15) & (DIMV - 1)]
                              : biasQ[(bn + wcn + j * 16 + l15) & (DIMV - 1)])
                       : 0.0f;
  float csum[4] = {0.f, 0.f, 0.f, 0.f};

#pragma unroll
  for (int p = 0; p < 2; ++p) {
    if (prow == p) {
#pragma unroll
      for (int i = 0; i < 8; ++i) {
#pragma unroll
        for (int r = 0; r < 4; ++r) {
          const int row_l = i * 16 + rbase + r;
          float invdp = 1.0f, den = 0.f, mk = 0.f;
          if (EPI == 3) {
            invdp = 1.0f / denom[(size_t)h * N_NODES + bm + p * 128 + row_l];
            if (isK) {
              den = clampabs(2.0f * invdp - 1.0f, 1e-10f);
              mk = mask[bm + p * 128 + row_l];
            }
          }
#pragma unroll
          for (int j = 0; j < 4; ++j) {
            float val = acc[i][j][r];
            if (EPI == 3) {
              val = elup1((val + bb[j]) * invdp);
              if (isK) {
                val = den * val * mk;
                csum[j] += val;
              }
            }
            LB[row_l * 256 + wcn + j * 16 + l15] = f2b(val);
          }
        }
      }
    }
    __syncthreads();
#pragma unroll
    for (int it = 0; it < 8; ++it) {
      const int idx = it * 512 + t;
      const int row_l = idx >> 5, cq = idx & 31;
      uint4 v = *(const uint4*)&LB[row_l * 256 + cq * 8];
      *(uint4*)(dst + (size_t)(bm + p * 128 + row_l) * DIMV + coloff + cq * 8) = v;
    }
    __syncthreads();
  }
  if (EPI == 3 && isK) {
#pragma unroll
    for (int j = 0; j < 4; ++j)
      atomicAdd(&v2sum[(bn + wcn + j * 16 + l15) & (DIMV - 1)], csum[j]);
  }
}

// ---------- fused 3-term split GEMM: C = bf16(AhiBhi + AloBhi + AhiBlo) ----------
// 256x256 tile, BK=32, 8 waves, dbuf, swizzled LDS, coalesced epilogue. 128 KB LDS.
__global__ __launch_bounds__(512, 2) void gemm_split3(const ushort_t* __restrict__ Ahi,
                                                      const ushort_t* __restrict__ Alo,
                                                      const ushort_t* __restrict__ Bhi,
                                                      const ushort_t* __restrict__ Blo,
                                                      ushort_t* __restrict__ C) {
  __shared__ ushort_t LB[65536];  // AH:0 AL:16384 BH:32768 BL:49152, each [2][8192]
  const int bid = blockIdx.x;
  const int swz = (bid & 7) * 32 + (bid >> 3);  // nwg = 256
  const int bm = (swz >> 2) * 256;
  const int bn = (swz & 3) * 256;
  const int t = threadIdx.x;
  const int w = t >> 6, lane = t & 63, l15 = lane & 15;
  const int wr = (w >> 2) * 128;
  const int wcn = (w & 3) * 64;
  const int kks = (((lane >> 4) ^ ((lane >> 1) & 3)) << 3);
  const int sksw = (((lane & 3) ^ ((lane >> 3) & 3)) << 3);

  size_t goA[2], goB[2];
  int lofs[2];
#pragma unroll
  for (int c = 0; c < 2; ++c) {
    const int ch = w + 8 * c;
    lofs[c] = ch * 512 + lane * 8;
    goA[c] = (size_t)(bm + ch * 16 + (lane >> 2)) * DIMV + sksw;
    goB[c] = (size_t)(bn + ch * 16 + (lane >> 2)) * DIMV + sksw;
  }

#define STAGE_S(buf, k0)                                             \
  do {                                                               \
    _Pragma("unroll") for (int c = 0; c < 2; ++c) {                  \
      GLD16(Ahi + goA[c] + (k0), &LB[(buf)*8192 + lofs[c]]);         \
      GLD16(Alo + goA[c] + (k0), &LB[16384 + (buf)*8192 + lofs[c]]); \
      GLD16(Bhi + goB[c] + (k0), &LB[32768 + (buf)*8192 + lofs[c]]); \
      GLD16(Blo + goB[c] + (k0), &LB[49152 + (buf)*8192 + lofs[c]]); \
    }                                                                \
  } while (0)

  f32x4 acc[8][4];
#pragma unroll
  for (int i = 0; i < 8; ++i)
#pragma unroll
    for (int j = 0; j < 4; ++j) acc[i][j] = (f32x4){0.f, 0.f, 0.f, 0.f};

  STAGE_S(0, 0);
  __syncthreads();
  int cur = 0;
  for (int k0 = 0; k0 < DIMV; k0 += 32) {
    if (k0 + 32 < DIMV) STAGE_S(cur ^ 1, k0 + 32);
    short8 bfH[4], bfL[4];
#pragma unroll
    for (int j = 0; j < 4; ++j) {
      bfH[j] = *(const short8*)&LB[32768 + cur * 8192 + (wcn + j * 16 + l15) * 32 + kks];
      bfL[j] = *(const short8*)&LB[49152 + cur * 8192 + (wcn + j * 16 + l15) * 32 + kks];
    }
#pragma unroll
    for (int i = 0; i < 8; ++i) {
      short8 afH = *(const short8*)&LB[cur * 8192 + (wr + i * 16 + l15) * 32 + kks];
      short8 afL = *(const short8*)&LB[16384 + cur * 8192 + (wr + i * 16 + l15) * 32 + kks];
#pragma unroll
      for (int j = 0; j < 4; ++j) {
        acc[i][j] = __builtin_amdgcn_mfma_f32_16x16x32_bf16(afH, bfH[j], acc[i][j], 0, 0, 0);
        acc[i][j] = __builtin_amdgcn_mfma_f32_16x16x32_bf16(afL, bfH[j], acc[i][j], 0, 0, 0);
        acc[i][j] = __builtin_amdgcn_mfma_f32_16x16x32_bf16(afH, bfL[j], acc[i][j], 0, 0, 0);
      }
    }
    __syncthreads();
    cur ^= 1;
  }
#undef STAGE_S

  // coalesced epilogue via LDS [128][256] (reuses first 64KB)
  const int rbase = (lane >> 4) * 4;
  const int prow = w >> 2;
#pragma unroll
  for (int p = 0; p < 2; ++p) {
    if (prow == p) {
#pragma unroll
      for (int i = 0; i < 8; ++i)
#pragma unroll
        for (int r = 0; r < 4; ++r) {
          const int row_l = i * 16 + rbase + r;
#pragma unroll
          for (int j = 0; j < 4; ++j)
            LB[row_l * 256 + wcn + j * 16 + l15] = f2b(acc[i][j][r]);
        }
    }
    __syncthreads();
#pragma unroll
    for (int it = 0; it < 8; ++it) {
      const int idx = it * 512 + t;
      const int row_l = idx >> 5, cq = idx & 31;
      uint4 v = *(const uint4*)&LB[row_l * 256 + cq * 8];
      *(uint4*)(C + (size_t)(bm + p * 128 + row_l) * DIMV + bn + cq * 8) = v;
    }
    __syncthreads();
  }
}

// ---------- row transform: mobius_matvec tail + kappa_relu (bf16 msrc, precomputed ||x||^2) ----------
template <bool BFDST>
__global__ __launch_bounds__(256) void rowtrans_kernel(const ushort_t* __restrict__ msrc,
                                                       const float* __restrict__ rowsq,
                                                       void* __restrict__ dstv,
                                                       float* __restrict__ denom) {
  __shared__ float red[4];
  __shared__ float orow[DIMV];
  const int row = blockIdx.x;
  const int t = threadIdx.x;
  uint2 mraw = ((const uint2*)(msrc + (size_t)row * DIMV))[t];
  ushort_t* mh = (ushort_t*)&mraw;
  float4 m4 = make_float4(b2f(mh[0]), b2f(mh[1]), b2f(mh[2]), b2f(mh[3]));
  float sm = m4.x * m4.x + m4.y * m4.y + m4.z * m4.z + m4.w * m4.w;
  sm = blockReduceSum(sm, red);
  float sx = rowsq[row];

  float xn = fmaxf(sqrtf(sx), 1e-15f);
  float mxn = fmaxf(sqrtf(sm), 1e-15f);
  float cx = fminf(xn, 1.0f - 1e-7f);
  float t1 = tanhf(mxn / xn * atanhf(cx));
  float s1 = t1 / mxn;

  float yn = fmaxf(fabsf(t1), 1e-15f);
  float a = atanhf(fminf(yn, 1.0f - 1e-7f)) / yn;
  float k1 = a * s1;
  float4 u = make_float4(fmaxf(k1 * m4.x, 0.0f), fmaxf(k1 * m4.y, 0.0f),
                         fmaxf(k1 * m4.z, 0.0f), fmaxf(k1 * m4.w, 0.0f));
  float su = u.x * u.x + u.y * u.y + u.z * u.z + u.w * u.w;
  su = blockReduceSum(su, red);

  float un = fmaxf(sqrtf(su), 1e-15f);
  float t2 = tanhf(un);
  float s2 = t2 / un;
  if (t2 > 0.996f) s2 *= 0.996f / t2;
  float4 o = make_float4(s2 * u.x, s2 * u.y, s2 * u.z, s2 * u.w);
  if (BFDST) {
    ushort_t h[4] = {f2b(o.x), f2b(o.y), f2b(o.z), f2b(o.w)};
    ((uint2*)((ushort_t*)dstv + (size_t)row * DIMV))[t] = *(uint2*)h;
  } else {
    ((float4*)((float*)dstv + (size_t)row * DIMV))[t] = o;
  }

  if (denom) {
    ((float4*)orow)[t] = o;
    __syncthreads();
    if (t < NHEADS) {
      float s = 0.0f;
#pragma unroll
      for (int i = 0; i < HEADD; ++i) {
        float v = orow[t * HEADD + i];
        s = fmaf(v, v, s);
      }
      denom[t * N_NODES + row] = fmaxf(1.0f - s, 1e-15f);
    }
  }
}

// ---------- ctxT[h][e][d] = sum_n v2[h,n,d] * (gamma/den * mask * V)[h,n,e]  (v2,V bf16) ----------
__global__ __launch_bounds__(256) void context_kernel(const ushort_t* __restrict__ v2buf,
                                                      const ushort_t* __restrict__ vbuf,
                                                      const float* __restrict__ denom,
                                                      const float* __restrict__ mask,
                                                      float* __restrict__ ctxT) {
  __shared__ float s2[64][65];
  __shared__ float sx[64][65];
  const int h = blockIdx.y;
  const int t = threadIdx.x;
  const int d0 = (t >> 4) * 4;
  const int e0 = (t & 15) * 4;
  float acc[4][4];
#pragma unroll
  for (int i = 0; i < 4; ++i)
#pragma unroll
    for (int j = 0; j < 4; ++j) acc[i][j] = 0.0f;

  const int rbase = blockIdx.x * 512;
  for (int c = 0; c < 8; ++c) {
#pragma unroll
    for (int i = 0; i < 4; ++i) {
      int f = i * 256 + t;
      int r = f >> 4;
      int cc = (f & 15) * 4;
      int row = rbase + c * 64 + r;
      uint2 araw = *(const uint2*)(v2buf + (size_t)row * DIMV + h * HEADD + cc);
      ushort_t* ah = (ushort_t*)&araw;
      s2[r][cc + 0] = b2f(ah[0]); s2[r][cc + 1] = b2f(ah[1]);
      s2[r][cc + 2] = b2f(ah[2]); s2[r][cc + 3] = b2f(ah[3]);
      float dp = denom[(size_t)h * N_NODES + row];
      float gamma = 2.0f / dp;
      float den = clampabs(gamma - 1.0f, 1e-10f);
      float c1 = gamma / den * mask[row];
      uint2 braw = *(const uint2*)(vbuf + (size_t)row * DIMV + h * HEADD + cc);
      ushort_t* bh = (ushort_t*)&braw;
      sx[r][cc + 0] = c1 * b2f(bh[0]); sx[r][cc + 1] = c1 * b2f(bh[1]);
      sx[r][cc + 2] = c1 * b2f(bh[2]); sx[r][cc + 3] = c1 * b2f(bh[3]);
    }
    __syncthreads();
    for (int r = 0; r < 64; ++r) {
      float av[4], bv[4];
#pragma unroll
      for (int i = 0; i < 4; ++i) av[i] = s2[r][d0 + i];
#pragma unroll
      for (int j = 0; j < 4; ++j) bv[j] = sx[r][e0 + j];
#pragma unroll
      for (int i = 0; i < 4; ++i)
#pragma unroll
        for (int j = 0; j < 4; ++j) acc[i][j] = fmaf(av[i], bv[j], acc[i][j]);
    }
    __syncthreads();
  }
#pragma unroll
  for (int i = 0; i < 4; ++i)
#pragma unroll
    for (int j = 0; j < 4; ++j)
      atomicAdd(&ctxT[h * 4096 + (e0 + j) * 64 + (d0 + i)], acc[i][j]);
}

// ---------- out (MFMA): [out|D] = v1 @ [ctx|v2sum]; tail; emit combHi/Lo + rownorm atomics ----------
__global__ __launch_bounds__(256) void out_mfma_kernel(const ushort_t* __restrict__ v1bf,
                                                       const float* __restrict__ v2sum,
                                                       const float* __restrict__ ctxT,
                                                       ushort_t* __restrict__ combHi,
                                                       ushort_t* __restrict__ combLo,
                                                       float* __restrict__ combnorm) {
  __shared__ ushort_t Blds[80][88];
  const int h = blockIdx.y;
  const int bm = blockIdx.x * 256;
  const int t = threadIdx.x;
  const int w = t >> 6, lane = t & 63, l15 = lane & 15;
  const int kk = (lane >> 4) * 8;

  for (int idx = t; idx < 80 * 64; idx += 256) {
    int e = idx >> 6, d = idx & 63;
    float v = 0.0f;
    if (e < 64) v = ctxT[h * 4096 + e * 64 + d];
    else if (e == 64) v = v2sum[h * 64 + d];
    Blds[e][d] = f2b(v);
  }
  __syncthreads();

  f32x4 acc[4][5];
#pragma unroll
  for (int i = 0; i < 4; ++i)
#pragma unroll
    for (int j = 0; j < 5; ++j) acc[i][j] = (f32x4){0.f, 0.f, 0.f, 0.f};
#pragma unroll
  for (int ks = 0; ks < 2; ++ks) {
    short8 bfr[5];
#pragma unroll
    for (int j = 0; j < 5; ++j) bfr[j] = *(const short8*)&Blds[j * 16 + l15][ks * 32 + kk];
#pragma unroll
    for (int i = 0; i < 4; ++i) {
      short8 af = *(const short8*)(v1bf + (size_t)(bm + w * 64 + i * 16 + l15) * DIMV +
                                   h * HEADD + ks * 32 + kk);
#pragma unroll
      for (int j = 0; j < 5; ++j)
        acc[i][j] = __builtin_amdgcn_mfma_f32_16x16x32_bf16(af, bfr[j], acc[i][j], 0, 0, 0);
    }
  }

  const int g4 = (lane >> 4) * 4;
#pragma unroll
  for (int i = 0; i < 4; ++i) {
#pragma unroll
    for (int r = 0; r < 4; ++r) {
      const int row = bm + w * 64 + i * 16 + g4 + r;
      float D = __shfl(acc[i][4][r], lane & 48);
      float Dinv = 1.0f / (D == 0.0f ? 1e-5f : D);
      float o[4];
      float s = 0.0f;
#pragma unroll
      for (int j = 0; j < 4; ++j) {
        o[j] = acc[i][j][r] * Dinv;
        s = fmaf(o[j], o[j], s);
      }
      s += __shfl_xor(s, 1); s += __shfl_xor(s, 2);
      s += __shfl_xor(s, 4); s += __shfl_xor(s, 8);
      float n1 = fmaxf(sqrtf(s), 1e-15f);
      float sc = 1.0f;
      if (n1 > 0.996f) sc = 0.996f / n1;
      float xn = fmaxf(fminf(n1, 0.996f), 1e-15f);
      float cx = fminf(xn, 1.0f - 1e-7f);
      float t2 = tanhf(0.5f * atanhf(cx));
      sc *= t2 / xn;
      if (t2 > 0.996f) sc *= 0.996f / t2;
      if (l15 == 0) atomicAdd(&combnorm[row], s * sc * sc);
#pragma unroll
      for (int j = 0; j < 4; ++j) {
        float ov = o[j] * sc;
        size_t off = (size_t)row * DIMV + h * HEADD + j * 16 + l15;
        ushort_t hi = f2b(ov);
        combHi[off] = hi;
        combLo[off] = f2b(ov - b2f(hi));
      }
    }
  }
}

// ---------- launch ----------

extern "C" void kernel_launch(void* const* d_in, const int* in_sizes, int n_in,
                              void* d_out, int out_size, void* d_ws, size_t ws_size,
                              hipStream_t stream) {
  const float* X = (const float*)d_in[0];
  const float* mask = (const float*)d_in[1];
  const float* Wq = (const float*)d_in[2];
  const float* bq = (const float*)d_in[3];
  const float* Wk = (const float*)d_in[4];
  const float* bk = (const float*)d_in[5];
  const float* Wv = (const float*)d_in[6];
  const float* Wff = (const float*)d_in[7];
  float* out = (float*)d_out;

  const size_t MAT = (size_t)N_NODES * DIMV;
  char* p = (char*)d_ws;
  // R1 (64MB): first half v1bf (QK epi out); second half mxV bf16, later combnorm
  ushort_t* v1bf = (ushort_t*)p;
  ushort_t* mxV = (ushort_t*)(p + MAT * 2);
  float* combnorm = (float*)(p + MAT * 2);
  p += MAT * 4;
  // R2 (64MB): xnormsq (early) / v2bf (QK epi out) / combHi+combLo (after context)
  float* xnormsq = (float*)p;
  ushort_t* v2bf = (ushort_t*)p;
  ushort_t* combHi = (ushort_t*)p;
  ushort_t* combLo = combHi + MAT;
  p += MAT * 4;
  // R3 (32MB): Vbf; later WffHi/WffLo
  ushort_t* Vbf = (ushort_t*)p;
  ushort_t* WffHi = Vbf;
  ushort_t* WffLo = Vbf + (size_t)DIMV * DIMV;
  p += MAT * 2;
  // R4 (32MB): Xbf; later outBf (split3 out)
  ushort_t* Xbf = (ushort_t*)p;
  ushort_t* outBf = Xbf;
  p += MAT * 2;
  float* denom = (float*)p;  p += (size_t)NHEADS * N_NODES * 4;
  float* v2sum = (float*)p;  p += 1024 * 4;
  float* ctxT = (float*)p;   p += (size_t)NHEADS * 4096 * 4;
  const size_t need = (size_t)(p - (char*)d_ws);
  if (ws_size < need) return;

  // W^T bf16 scratch inside d_out (free until the final rowtrans writes it):
  ushort_t* Wt = (ushort_t*)d_out;            // Wv^T, later Wq^T (rows 0..1023)
  ushort_t* WtK = Wt + (size_t)DIMV * DIMV;   // Wk^T (rows 1024..2047 of stacked QK)

  dim3 tgrid(32, 32);

  cvt_norm_kernel<<<N_NODES, 256, 0, stream>>>(X, Xbf, xnormsq);
  // V path: mxV bf16, then rowtrans -> Vbf + denom
  transW_kernel<false><<<tgrid, 256, 0, stream>>>(Wv, Wt, nullptr);
  gemm_bf<0, 4><<<256, 512, 0, stream>>>(Xbf, Wt, nullptr, nullptr, nullptr, nullptr,
                                         nullptr, mxV, nullptr);
  rowtrans_kernel<true><<<N_NODES, 256, 0, stream>>>(mxV, xnormsq, Vbf, denom);
  // zero accumulators (v2sum+ctxT contiguous; combnorm over dead mxV)
  hipMemsetAsync(v2sum, 0, (1024 + 4096 * NHEADS) * sizeof(float), stream);
  hipMemsetAsync(combnorm, 0, N_NODES * sizeof(float), stream);
  // QK fused: stacked [Wq^T; Wk^T], epilogue emits v1 (cols<1024) and v2 + v2sum (cols>=1024)
  transW_kernel<false><<<tgrid, 256, 0, stream>>>(Wq, Wt, nullptr);
  transW_kernel<false><<<tgrid, 256, 0, stream>>>(Wk, WtK, nullptr);
  gemm_bf<3, 8><<<512, 512, 0, stream>>>(Xbf, Wt, bq, bk, denom, mask, v2sum, v1bf, v2bf);
  // context (transposed output)
  context_kernel<<<dim3(32, NHEADS), 256, 0, stream>>>(v2bf, Vbf, denom, mask, ctxT);
  // attention out -> combHi/Lo + row norms
  out_mfma_kernel<<<dim3(N_NODES / 256, NHEADS), 256, 0, stream>>>(v1bf, v2sum, ctxT, combHi,
                                                                   combLo, combnorm);
  // final: fused 3-term split GEMM -> outBf, then rowtrans -> d_out
  transW_kernel<true><<<tgrid, 256, 0, stream>>>(Wff, WffHi, WffLo);
  gemm_split3<<<256, 512, 0, stream>>>(combHi, combLo, WffHi, WffLo, outBf);
  rowtrans_kernel<false><<<N_NODES, 256, 0, stream>>>(outBf, combnorm, out, nullptr);
}

// Round 10
// 504.489 us; speedup vs baseline: 1.1051x; 1.0142x over previous
//
#include <hip/hip_runtime.h>
#include <hip/hip_bf16.h>
#include <math.h>

#define N_NODES 16384
#define DIMV 1024
#define NHEADS 16
#define HEADD 64

typedef __attribute__((ext_vector_type(8))) short short8;
typedef __attribute__((ext_vector_type(4))) float f32x4;
typedef unsigned short ushort_t;

// async global->LDS, 16B per lane
#define GLD16(gptr, lptr)                                                                 \
  __builtin_amdgcn_global_load_lds((const __attribute__((address_space(1))) void*)(gptr), \
                                   (__attribute__((address_space(3))) void*)(lptr), 16, 0, 0)

#define SCHED0() __builtin_amdgcn_sched_barrier(0)
#define SBAR() __builtin_amdgcn_s_barrier()
#define DSREAD(dst, addr) \
  asm volatile("ds_read_b128 %0, %1" : "=v"(dst) : "v"(addr) : "memory")
#define WAITLGKM2() asm volatile("s_waitcnt lgkmcnt(2)" ::: "memory")
#define WAITLGKM0() asm volatile("s_waitcnt lgkmcnt(0)" ::: "memory")
#define WAITVM4() asm volatile("s_waitcnt vmcnt(4)" ::: "memory")

__device__ __forceinline__ unsigned lds_base_addr(const void* p) {
  return (unsigned)(uintptr_t)(const __attribute__((address_space(3))) void*)p;
}

// ---------- helpers ----------

__device__ __forceinline__ float waveReduceSum(float v) {
#pragma unroll
  for (int m = 32; m; m >>= 1) v += __shfl_xor(v, m);
  return v;
}

__device__ __forceinline__ float blockReduceSum(float v, float* red) {
  float w = waveReduceSum(v);
  __syncthreads();
  if ((threadIdx.x & 63) == 0) red[threadIdx.x >> 6] = w;
  __syncthreads();
  return red[0] + red[1] + red[2] + red[3];
}

__device__ __forceinline__ float elup1(float z) {
  return z > 0.0f ? z + 1.0f : expm1f(z) + 1.0f;
}

__device__ __forceinline__ float clampabs(float x, float eps) {
  float s = (x >= 0.0f) ? 1.0f : -1.0f;
  return s * fmaxf(fabsf(x), eps);
}

// fp32 -> bf16 bits, RNE
__device__ __forceinline__ ushort_t f2b(float x) {
  unsigned u = __float_as_uint(x);
  unsigned r = (u + 0x7FFFu + ((u >> 16) & 1u)) >> 16;
  return (ushort_t)r;
}
__device__ __forceinline__ float b2f(ushort_t h) {
  return __uint_as_float(((unsigned)h) << 16);
}

// ---------- X -> bf16 + row sumsq (one block per row) ----------
__global__ __launch_bounds__(256) void cvt_norm_kernel(const float* __restrict__ src,
                                                       ushort_t* __restrict__ dst,
                                                       float* __restrict__ rowsq) {
  __shared__ float red[4];
  const int row = blockIdx.x;
  const int t = threadIdx.x;
  float4 x4 = ((const float4*)(src + (size_t)row * DIMV))[t];
  ushort_t h[4] = {f2b(x4.x), f2b(x4.y), f2b(x4.z), f2b(x4.w)};
  ((uint2*)(dst + (size_t)row * DIMV))[t] = *(uint2*)h;
  float s = x4.x * x4.x + x4.y * x4.y + x4.z * x4.z + x4.w * x4.w;
  s = blockReduceSum(s, red);
  if (t == 0) rowsq[row] = s;
}

// ---------- weight transpose -> bf16 (hi, and optional lo residual) ----------
template <bool LO>
__global__ __launch_bounds__(256) void transW_kernel(const float* __restrict__ src,
                                                     ushort_t* __restrict__ hi,
                                                     ushort_t* __restrict__ lo) {
  __shared__ float tile[32][33];
  const int bx = blockIdx.x * 32, by = blockIdx.y * 32;
  const int tx = threadIdx.x & 31, ty = threadIdx.x >> 5;
#pragma unroll
  for (int i = 0; i < 32; i += 8) tile[ty + i][tx] = src[(size_t)(by + ty + i) * DIMV + bx + tx];
  __syncthreads();
#pragma unroll
  for (int i = 0; i < 32; i += 8) {
    float v = tile[tx][ty + i];
    ushort_t h = f2b(v);
    hi[(size_t)(bx + ty + i) * DIMV + by + tx] = h;
    if (LO) lo[(size_t)(bx + ty + i) * DIMV + by + tx] = f2b(v - b2f(h));
  }
}

// k-unit swizzle (16B units within a 64B row): LDS[row][u] holds global unit u ^ ((row>>1)&3).
// Source: lane loads global unit (lane&3)^((lane>>3)&3) (row-in-chunk = lane>>2).
// Read: unit (lane>>4) of row (..+l15) lives at unit (lane>>4)^((lane>>1)&3) -> 2 lanes/bank.

// ---------- bf16 MFMA GEMM, 128x128 tile, 4 waves, 4-buffer LDS ring, pipelined phases ----
// A: [M][1024] bf16, Bt: [NB*128 n][1024 k] bf16. Wave tile 64x64 = acc[4][4] (64 AGPR).
// Per K-step (BK=32): ph0 {read bf0..3 + af23(cur); stage A(kt+3); lgkm(2); 8 MFMA rows 0-1}
//                     ph1 {read af01(buf kt+1); stage B(kt+3); lgkm(2); 8 MFMA rows 2-3;
//                          vmcnt(4); s_barrier}
// 4-ring: buf kt+1 is vmcnt-retired + barrier-published at end of step kt-1 -> cross-read safe.
// EPI 0: Cq = bf16(acc); EPI 3: QK fused (v1 / v2+v2sum). Coalesced epilogue via LDS.
template <int EPI, int NB>
__global__ __launch_bounds__(256) void gemm_bf(const ushort_t* __restrict__ A,
                                               const ushort_t* __restrict__ Bt,
                                               const float* __restrict__ biasQ,
                                               const float* __restrict__ biasK,
                                               const float* __restrict__ denom,
                                               const float* __restrict__ mask,
                                               float* __restrict__ v2sum,
                                               ushort_t* __restrict__ Cq,
                                               ushort_t* __restrict__ Ck) {
  __shared__ ushort_t LB[32768];  // 64 KB: A bufs at b*8192 B, B bufs at 32768 + b*8192 B
  const int bid = blockIdx.x;
  const int nwg = NB * 128;
  const int swz = (bid & 7) * (nwg / 8) + (bid >> 3);
  const int bm = (swz / NB) * 128;
  const int bn = (swz % NB) * 128;
  const int t = threadIdx.x;
  const int w = t >> 6, lane = t & 63, l15 = lane & 15;
  const int wr = (w >> 1) * 64;
  const int wc = (w & 1) * 64;
  const int kkb = (((lane >> 4) ^ ((lane >> 1) & 3)) << 4);   // fragment unit byte offset
  const int sksw = (((lane & 3) ^ ((lane >> 3) & 3)) << 3);   // staging src k-offset (elems)

  // staging: 8 chunks of 16 rows x 64B per operand; wave w takes chunks w and w+4.
  const ushort_t* gA0 = A + (size_t)(bm + w * 16 + (lane >> 2)) * DIMV + sksw;
  const ushort_t* gA1 = A + (size_t)(bm + (w + 4) * 16 + (lane >> 2)) * DIMV + sksw;
  const ushort_t* gB0 = Bt + (size_t)(bn + w * 16 + (lane >> 2)) * DIMV + sksw;
  const ushort_t* gB1 = Bt + (size_t)(bn + (w + 4) * 16 + (lane >> 2)) * DIMV + sksw;
  char* lA0 = (char*)LB + w * 1024 + lane * 16;
  char* lA1 = (char*)LB + (w + 4) * 1024 + lane * 16;
  char* lB0 = (char*)LB + 32768 + w * 1024 + lane * 16;
  char* lB1 = (char*)LB + 32768 + (w + 4) * 1024 + lane * 16;

  const unsigned lbase = lds_base_addr(LB);
  unsigned arow[4], brow[4];
#pragma unroll
  for (int f = 0; f < 4; ++f) arow[f] = (unsigned)((wr + f * 16 + l15) * 64 + kkb);
#pragma unroll
  for (int j = 0; j < 4; ++j) brow[j] = (unsigned)((wc + j * 16 + l15) * 64 + kkb + 32768);

  f32x4 acc[4][4];
#pragma unroll
  for (int i = 0; i < 4; ++i)
#pragma unroll
    for (int j = 0; j < 4; ++j) acc[i][j] = (f32x4){0.f, 0.f, 0.f, 0.f};

  // prologue: stage tiles 0,1,2; retire tiles 0,1; preload af_cur of tile 0
  GLD16(gA0, lA0); GLD16(gA1, lA1); GLD16(gB0, lB0); GLD16(gB1, lB1);
  GLD16(gA0 + 32, lA0 + 8192); GLD16(gA1 + 32, lA1 + 8192);
  GLD16(gB0 + 32, lB0 + 8192); GLD16(gB1 + 32, lB1 + 8192);
  GLD16(gA0 + 64, lA0 + 16384); GLD16(gA1 + 64, lA1 + 16384);
  GLD16(gB0 + 64, lB0 + 16384); GLD16(gB1 + 64, lB1 + 16384);
  SCHED0();
  WAITVM4();
  SBAR();
  SCHED0();

  short8 bf0, bf1, bf2, bf3, afc0, afc1, afn0, afn1, aff0, aff1;
  DSREAD(afc0, lbase + arow[0]);
  DSREAD(afc1, lbase + arow[1]);

  int cur = 0;
  for (int kt = 0; kt < 32; ++kt) {
    const unsigned ab = lbase + (unsigned)(cur * 8192);
    const int nxt = (kt == 31) ? cur : ((cur + 1) & 3);
    const unsigned abn = lbase + (unsigned)(nxt * 8192);
    const int kg = (kt + 3) * 32;
    const int sboff = ((kt + 3) & 3) * 8192;
    // ---- phase 0 ----
    DSREAD(bf0, ab + brow[0]);
    DSREAD(bf1, ab + brow[1]);
    DSREAD(bf2, ab + brow[2]);
    DSREAD(bf3, ab + brow[3]);
    DSREAD(afn0, ab + arow[2]);
    DSREAD(afn1, ab + arow[3]);
    if (kt <= 28) {
      GLD16(gA0 + kg, lA0 + sboff);
      GLD16(gA1 + kg, lA1 + sboff);
    }
    WAITLGKM2();  // afc(old aff) + bf retired; afn in flight
    SCHED0();
    __builtin_amdgcn_s_setprio(1);
    acc[0][0] = __builtin_amdgcn_mfma_f32_16x16x32_bf16(afc0, bf0, acc[0][0], 0, 0, 0);
    acc[0][1] = __builtin_amdgcn_mfma_f32_16x16x32_bf16(afc0, bf1, acc[0][1], 0, 0, 0);
    acc[0][2] = __builtin_amdgcn_mfma_f32_16x16x32_bf16(afc0, bf2, acc[0][2], 0, 0, 0);
    acc[0][3] = __builtin_amdgcn_mfma_f32_16x16x32_bf16(afc0, bf3, acc[0][3], 0, 0, 0);
    acc[1][0] = __builtin_amdgcn_mfma_f32_16x16x32_bf16(afc1, bf0, acc[1][0], 0, 0, 0);
    acc[1][1] = __builtin_amdgcn_mfma_f32_16x16x32_bf16(afc1, bf1, acc[1][1], 0, 0, 0);
    acc[1][2] = __builtin_amdgcn_mfma_f32_16x16x32_bf16(afc1, bf2, acc[1][2], 0, 0, 0);
    acc[1][3] = __builtin_amdgcn_mfma_f32_16x16x32_bf16(afc1, bf3, acc[1][3], 0, 0, 0);
    __builtin_amdgcn_s_setprio(0);
    // ---- phase 1 ----
    DSREAD(aff0, abn + arow[0]);
    DSREAD(aff1, abn + arow[1]);
    if (kt <= 28) {
      GLD16(gB0 + kg, lB0 + sboff);
      GLD16(gB1 + kg, lB1 + sboff);
    }
    WAITLGKM2();  // afn retired; aff in flight
    SCHED0();
    __builtin_amdgcn_s_setprio(1);
    acc[2][0] = __builtin_amdgcn_mfma_f32_16x16x32_bf16(afn0, bf0, acc[2][0], 0, 0, 0);
    acc[2][1] = __builtin_amdgcn_mfma_f32_16x16x32_bf16(afn0, bf1, acc[2][1], 0, 0, 0);
    acc[2][2] = __builtin_amdgcn_mfma_f32_16x16x32_bf16(afn0, bf2, acc[2][2], 0, 0, 0);
    acc[2][3] = __builtin_amdgcn_mfma_f32_16x16x32_bf16(afn0, bf3, acc[2][3], 0, 0, 0);
    acc[3][0] = __builtin_amdgcn_mfma_f32_16x16x32_bf16(afn1, bf0, acc[3][0], 0, 0, 0);
    acc[3][1] = __builtin_amdgcn_mfma_f32_16x16x32_bf16(afn1, bf1, acc[3][1], 0, 0, 0);
    acc[3][2] = __builtin_amdgcn_mfma_f32_16x16x32_bf16(afn1, bf2, acc[3][2], 0, 0, 0);
    acc[3][3] = __builtin_amdgcn_mfma_f32_16x16x32_bf16(afn1, bf3, acc[3][3], 0, 0, 0);
    __builtin_amdgcn_s_setprio(0);
    SCHED0();
    WAITVM4();  // retire tile kt+2's stages; tile kt+3's 4 loads stay in flight
    SBAR();
    SCHED0();
    afc0 = aff0;
    afc1 = aff1;
    cur = (cur + 1) & 3;
  }
  WAITLGKM0();  // retire dangling aff reads before LDS reuse

  // ---- epilogue: math -> LDS [128][128] bf16 -> coalesced global stores ----
  const int rbase = (lane >> 4) * 4;
  const bool isK = (EPI == 3) && (bn >= DIMV);
  const int h = ((bn + wc) >> 6) & (NHEADS - 1);
  ushort_t* dst = (EPI == 3 && isK) ? Ck : Cq;
  const int coloff = (EPI == 3) ? (bn & (DIMV - 1)) : bn;
  float bb[4];
#pragma unroll
  for (int j = 0; j < 4; ++j)
    bb[j] = (EPI == 3) ? (isK ? biasK[(bn + wc + j * 16 + l15) & (DIMV - 1)]
                              : biasQ[(bn + wc + j * 16 + l15) & (DIMV - 1)])
                       : 0.0f;
  float csum[4] = {0.f, 0.f, 0.f, 0.f};
#pragma unroll
  for (int i = 0; i < 4; ++i) {
#pragma unroll
    for (int r = 0; r < 4; ++r) {
      const int row_l = wr + i * 16 + rbase + r;
      float invdp = 1.0f, den = 0.f, mk = 0.f;
      if (EPI == 3) {
        invdp = 1.0f / denom[(size_t)h * N_NODES + bm + row_l];
        if (isK) {
          den = clampabs(2.0f * invdp - 1.0f, 1e-10f);
          mk = mask[bm + row_l];
        }
      }
#pragma unroll
      for (int j = 0; j < 4; ++j) {
        float val = acc[i][j][r];
        if (EPI == 3) {
          val = elup1((val + bb[j]) * invdp);
          if (isK) {
            val = den * val * mk;
            csum[j] += val;
          }
        }
        LB[row_l * 128 + wc + j * 16 + l15] = f2b(val);
      }
    }
  }
  __syncthreads();
#pragma unroll
  for (int it = 0; it < 8; ++it) {
    const int idx = it * 256 + t;
    const int row_l = idx >> 4, cq = idx & 15;
    uint4 v = *(const uint4*)&LB[row_l * 128 + cq * 8];
    *(uint4*)(dst + (size_t)(bm + row_l) * DIMV + coloff + cq * 8) = v;
  }
  if (EPI == 3 && isK) {
#pragma unroll
    for (int j = 0; j < 4; ++j)
      atomicAdd(&v2sum[(bn + wc + j * 16 + l15) & (DIMV - 1)], csum[j]);
  }
}

// ---------- fused 3-term split GEMM: C = bf16(AhiBhi + AloBhi + AhiBlo) ----------
// 256x256 tile, BK=32, 8 waves, dbuf, swizzled LDS, coalesced epilogue. 128 KB LDS.
__global__ __launch_bounds__(512, 2) void gemm_split3(const ushort_t* __restrict__ Ahi,
                                                      const ushort_t* __restrict__ Alo,
                                                      const ushort_t* __restrict__ Bhi,
                                                      const ushort_t* __restrict__ Blo,
                                                      ushort_t* __restrict__ C) {
  __shared__ ushort_t LB[65536];  // AH:0 AL:16384 BH:32768 BL:49152, each [2][8192]
  const int bid = blockIdx.x;
  const int swz = (bid & 7) * 32 + (bid >> 3);  // nwg = 256
  const int bm = (swz >> 2) * 256;
  const int bn = (swz & 3) * 256;
  const int t = threadIdx.x;
  const int w = t >> 6, lane = t & 63, l15 = lane & 15;
  const int wr = (w >> 2) * 128;
  const int wcn = (w & 3) * 64;
  const int kks = (((lane >> 4) ^ ((lane >> 1) & 3)) << 3);
  const int sksw = (((lane & 3) ^ ((lane >> 3) & 3)) << 3);

  size_t goA[2], goB[2];
  int lofs[2];
#pragma unroll
  for (int c = 0; c < 2; ++c) {
    const int ch = w + 8 * c;
    lofs[c] = ch * 512 + lane * 8;
    goA[c] = (size_t)(bm + ch * 16 + (lane >> 2)) * DIMV + sksw;
    goB[c] = (size_t)(bn + ch * 16 + (lane >> 2)) * DIMV + sksw;
  }

#define STAGE_S(buf, k0)                                             \
  do {                                                               \
    _Pragma("unroll") for (int c = 0; c < 2; ++c) {                  \
      GLD16(Ahi + goA[c] + (k0), &LB[(buf)*8192 + lofs[c]]);         \
      GLD16(Alo + goA[c] + (k0), &LB[16384 + (buf)*8192 + lofs[c]]); \
      GLD16(Bhi + goB[c] + (k0), &LB[32768 + (buf)*8192 + lofs[c]]); \
      GLD16(Blo + goB[c] + (k0), &LB[49152 + (buf)*8192 + lofs[c]]); \
    }                                                                \
  } while (0)

  f32x4 acc[8][4];
#pragma unroll
  for (int i = 0; i < 8; ++i)
#pragma unroll
    for (int j = 0; j < 4; ++j) acc[i][j] = (f32x4){0.f, 0.f, 0.f, 0.f};

  STAGE_S(0, 0);
  __syncthreads();
  int cur = 0;
  for (int k0 = 0; k0 < DIMV; k0 += 32) {
    if (k0 + 32 < DIMV) STAGE_S(cur ^ 1, k0 + 32);
    short8 bfH[4], bfL[4];
#pragma unroll
    for (int j = 0; j < 4; ++j) {
      bfH[j] = *(const short8*)&LB[32768 + cur * 8192 + (wcn + j * 16 + l15) * 32 + kks];
      bfL[j] = *(const short8*)&LB[49152 + cur * 8192 + (wcn + j * 16 + l15) * 32 + kks];
    }
#pragma unroll
    for (int i = 0; i < 8; ++i) {
      short8 afH = *(const short8*)&LB[cur * 8192 + (wr + i * 16 + l15) * 32 + kks];
      short8 afL = *(const short8*)&LB[16384 + cur * 8192 + (wr + i * 16 + l15) * 32 + kks];
#pragma unroll
      for (int j = 0; j < 4; ++j) {
        acc[i][j] = __builtin_amdgcn_mfma_f32_16x16x32_bf16(afH, bfH[j], acc[i][j], 0, 0, 0);
        acc[i][j] = __builtin_amdgcn_mfma_f32_16x16x32_bf16(afL, bfH[j], acc[i][j], 0, 0, 0);
        acc[i][j] = __builtin_amdgcn_mfma_f32_16x16x32_bf16(afH, bfL[j], acc[i][j], 0, 0, 0);
      }
    }
    __syncthreads();
    cur ^= 1;
  }
#undef STAGE_S

  // coalesced epilogue via LDS [128][256] (reuses first 64KB)
  const int rbase = (lane >> 4) * 4;
  const int prow = w >> 2;
#pragma unroll
  for (int p = 0; p < 2; ++p) {
    if (prow == p) {
#pragma unroll
      for (int i = 0; i < 8; ++i)
#pragma unroll
        for (int r = 0; r < 4; ++r) {
          const int row_l = i * 16 + rbase + r;
#pragma unroll
          for (int j = 0; j < 4; ++j)
            LB[row_l * 256 + wcn + j * 16 + l15] = f2b(acc[i][j][r]);
        }
    }
    __syncthreads();
#pragma unroll
    for (int it = 0; it < 8; ++it) {
      const int idx = it * 512 + t;
      const int row_l = idx >> 5, cq = idx & 31;
      uint4 v = *(const uint4*)&LB[row_l * 256 + cq * 8];
      *(uint4*)(C + (size_t)(bm + p * 128 + row_l) * DIMV + bn + cq * 8) = v;
    }
    __syncthreads();
  }
}

// ---------- row transform: mobius_matvec tail + kappa_relu (bf16 msrc, precomputed ||x||^2) ----------
template <bool BFDST>
__global__ __launch_bounds__(256) void rowtrans_kernel(const ushort_t* __restrict__ msrc,
                                                       const float* __restrict__ rowsq,
                                                       void* __restrict__ dstv,
                                                       float* __restrict__ denom) {
  __shared__ float red[4];
  __shared__ float orow[DIMV];
  const int row = blockIdx.x;
  const int t = threadIdx.x;
  uint2 mraw = ((const uint2*)(msrc + (size_t)row * DIMV))[t];
  ushort_t* mh = (ushort_t*)&mraw;
  float4 m4 = make_float4(b2f(mh[0]), b2f(mh[1]), b2f(mh[2]), b2f(mh[3]));
  float sm = m4.x * m4.x + m4.y * m4.y + m4.z * m4.z + m4.w * m4.w;
  sm = blockReduceSum(sm, red);
  float sx = rowsq[row];

  float xn = fmaxf(sqrtf(sx), 1e-15f);
  float mxn = fmaxf(sqrtf(sm), 1e-15f);
  float cx = fminf(xn, 1.0f - 1e-7f);
  float t1 = tanhf(mxn / xn * atanhf(cx));
  float s1 = t1 / mxn;

  float yn = fmaxf(fabsf(t1), 1e-15f);
  float a = atanhf(fminf(yn, 1.0f - 1e-7f)) / yn;
  float k1 = a * s1;
  float4 u = make_float4(fmaxf(k1 * m4.x, 0.0f), fmaxf(k1 * m4.y, 0.0f),
                         fmaxf(k1 * m4.z, 0.0f), fmaxf(k1 * m4.w, 0.0f));
  float su = u.x * u.x + u.y * u.y + u.z * u.z + u.w * u.w;
  su = blockReduceSum(su, red);

  float un = fmaxf(sqrtf(su), 1e-15f);
  float t2 = tanhf(un);
  float s2 = t2 / un;
  if (t2 > 0.996f) s2 *= 0.996f / t2;
  float4 o = make_float4(s2 * u.x, s2 * u.y, s2 * u.z, s2 * u.w);
  if (BFDST) {
    ushort_t h[4] = {f2b(o.x), f2b(o.y), f2b(o.z), f2b(o.w)};
    ((uint2*)((ushort_t*)dstv + (size_t)row * DIMV))[t] = *(uint2*)h;
  } else {
    ((float4*)((float*)dstv + (size_t)row * DIMV))[t] = o;
  }

  if (denom) {
    ((float4*)orow)[t] = o;
    __syncthreads();
    if (t < NHEADS) {
      float s = 0.0f;
#pragma unroll
      for (int i = 0; i < HEADD; ++i) {
        float v = orow[t * HEADD + i];
        s = fmaf(v, v, s);
      }
      denom[t * N_NODES + row] = fmaxf(1.0f - s, 1e-15f);
    }
  }
}

// ---------- ctxT[h][e][d] = sum_n v2[h,n,d] * (gamma/den * mask * V)[h,n,e]  (v2,V bf16) ----------
__global__ __launch_bounds__(256) void context_kernel(const ushort_t* __restrict__ v2buf,
                                                      const ushort_t* __restrict__ vbuf,
                                                      const float* __restrict__ denom,
                                                      const float* __restrict__ mask,
                                                      float* __restrict__ ctxT) {
  __shared__ float s2[64][65];
  __shared__ float sx[64][65];
  const int h = blockIdx.y;
  const int t = threadIdx.x;
  const int d0 = (t >> 4) * 4;
  const int e0 = (t & 15) * 4;
  float acc[4][4];
#pragma unroll
  for (int i = 0; i < 4; ++i)
#pragma unroll
    for (int j = 0; j < 4; ++j) acc[i][j] = 0.0f;

  const int rbase = blockIdx.x * 512;
  for (int c = 0; c < 8; ++c) {
#pragma unroll
    for (int i = 0; i < 4; ++i) {
      int f = i * 256 + t;
      int r = f >> 4;
      int cc = (f & 15) * 4;
      int row = rbase + c * 64 + r;
      uint2 araw = *(const uint2*)(v2buf + (size_t)row * DIMV + h * HEADD + cc);
      ushort_t* ah = (ushort_t*)&araw;
      s2[r][cc + 0] = b2f(ah[0]); s2[r][cc + 1] = b2f(ah[1]);
      s2[r][cc + 2] = b2f(ah[2]); s2[r][cc + 3] = b2f(ah[3]);
      float dp = denom[(size_t)h * N_NODES + row];
      float gamma = 2.0f / dp;
      float den = clampabs(gamma - 1.0f, 1e-10f);
      float c1 = gamma / den * mask[row];
      uint2 braw = *(const uint2*)(vbuf + (size_t)row * DIMV + h * HEADD + cc);
      ushort_t* bh = (ushort_t*)&braw;
      sx[r][cc + 0] = c1 * b2f(bh[0]); sx[r][cc + 1] = c1 * b2f(bh[1]);
      sx[r][cc + 2] = c1 * b2f(bh[2]); sx[r][cc + 3] = c1 * b2f(bh[3]);
    }
    __syncthreads();
    for (int r = 0; r < 64; ++r) {
      float av[4], bv[4];
#pragma unroll
      for (int i = 0; i < 4; ++i) av[i] = s2[r][d0 + i];
#pragma unroll
      for (int j = 0; j < 4; ++j) bv[j] = sx[r][e0 + j];
#pragma unroll
      for (int i = 0; i < 4; ++i)
#pragma unroll
        for (int j = 0; j < 4; ++j) acc[i][j] = fmaf(av[i], bv[j], acc[i][j]);
    }
    __syncthreads();
  }
#pragma unroll
  for (int i = 0; i < 4; ++i)
#pragma unroll
    for (int j = 0; j < 4; ++j)
      atomicAdd(&ctxT[h * 4096 + (e0 + j) * 64 + (d0 + i)], acc[i][j]);
}

// ---------- out (MFMA): [out|D] = v1 @ [ctx|v2sum]; tail; emit combHi/Lo + rownorm atomics ----------
__global__ __launch_bounds__(256) void out_mfma_kernel(const ushort_t* __restrict__ v1bf,
                                                       const float* __restrict__ v2sum,
                                                       const float* __restrict__ ctxT,
                                                       ushort_t* __restrict__ combHi,
                                                       ushort_t* __restrict__ combLo,
                                                       float* __restrict__ combnorm) {
  __shared__ ushort_t Blds[80][88];
  const int h = blockIdx.y;
  const int bm = blockIdx.x * 256;
  const int t = threadIdx.x;
  const int w = t >> 6, lane = t & 63, l15 = lane & 15;
  const int kk = (lane >> 4) * 8;

  for (int idx = t; idx < 80 * 64; idx += 256) {
    int e = idx >> 6, d = idx & 63;
    float v = 0.0f;
    if (e < 64) v = ctxT[h * 4096 + e * 64 + d];
    else if (e == 64) v = v2sum[h * 64 + d];
    Blds[e][d] = f2b(v);
  }
  __syncthreads();

  f32x4 acc[4][5];
#pragma unroll
  for (int i = 0; i < 4; ++i)
#pragma unroll
    for (int j = 0; j < 5; ++j) acc[i][j] = (f32x4){0.f, 0.f, 0.f, 0.f};
#pragma unroll
  for (int ks = 0; ks < 2; ++ks) {
    short8 bfr[5];
#pragma unroll
    for (int j = 0; j < 5; ++j) bfr[j] = *(const short8*)&Blds[j * 16 + l15][ks * 32 + kk];
#pragma unroll
    for (int i = 0; i < 4; ++i) {
      short8 af = *(const short8*)(v1bf + (size_t)(bm + w * 64 + i * 16 + l15) * DIMV +
                                   h * HEADD + ks * 32 + kk);
#pragma unroll
      for (int j = 0; j < 5; ++j)
        acc[i][j] = __builtin_amdgcn_mfma_f32_16x16x32_bf16(af, bfr[j], acc[i][j], 0, 0, 0);
    }
  }

  const int g4 = (lane >> 4) * 4;
#pragma unroll
  for (int i = 0; i < 4; ++i) {
#pragma unroll
    for (int r = 0; r < 4; ++r) {
      const int row = bm + w * 64 + i * 16 + g4 + r;
      float D = __shfl(acc[i][4][r], lane & 48);
      float Dinv = 1.0f / (D == 0.0f ? 1e-5f : D);
      float o[4];
      float s = 0.0f;
#pragma unroll
      for (int j = 0; j < 4; ++j) {
        o[j] = acc[i][j][r] * Dinv;
        s = fmaf(o[j], o[j], s);
      }
      s += __shfl_xor(s, 1); s += __shfl_xor(s, 2);
      s += __shfl_xor(s, 4); s += __shfl_xor(s, 8);
      float n1 = fmaxf(sqrtf(s), 1e-15f);
      float sc = 1.0f;
      if (n1 > 0.996f) sc = 0.996f / n1;
      float xn = fmaxf(fminf(n1, 0.996f), 1e-15f);
      float cx = fminf(xn, 1.0f - 1e-7f);
      float t2 = tanhf(0.5f * atanhf(cx));
      sc *= t2 / xn;
      if (t2 > 0.996f) sc *= 0.996f / t2;
      if (l15 == 0) atomicAdd(&combnorm[row], s * sc * sc);
#pragma unroll
      for (int j = 0; j < 4; ++j) {
        float ov = o[j] * sc;
        size_t off = (size_t)row * DIMV + h * HEADD + j * 16 + l15;
        ushort_t hi = f2b(ov);
        combHi[off] = hi;
        combLo[off] = f2b(ov - b2f(hi));
      }
    }
  }
}

// ---------- launch ----------

extern "C" void kernel_launch(void* const* d_in, const int* in_sizes, int n_in,
                              void* d_out, int out_size, void* d_ws, size_t ws_size,
                              hipStream_t stream) {
  const float* X = (const float*)d_in[0];
  const float* mask = (const float*)d_in[1];
  const float* Wq = (const float*)d_in[2];
  const float* bq = (const float*)d_in[3];
  const float* Wk = (const float*)d_in[4];
  const float* bk = (const float*)d_in[5];
  const float* Wv = (const float*)d_in[6];
  const float* Wff = (const float*)d_in[7];
  float* out = (float*)d_out;

  const size_t MAT = (size_t)N_NODES * DIMV;
  char* p = (char*)d_ws;
  // R1 (64MB): first half v1bf (QK epi out); second half mxV bf16, later combnorm
  ushort_t* v1bf = (ushort_t*)p;
  ushort_t* mxV = (ushort_t*)(p + MAT * 2);
  float* combnorm = (float*)(p + MAT * 2);
  p += MAT * 4;
  // R2 (64MB): xnormsq (early) / v2bf (QK epi out) / combHi+combLo (after context)
  float* xnormsq = (float*)p;
  ushort_t* v2bf = (ushort_t*)p;
  ushort_t* combHi = (ushort_t*)p;
  ushort_t* combLo = combHi + MAT;
  p += MAT * 4;
  // R3 (32MB): Vbf; later WffHi/WffLo
  ushort_t* Vbf = (ushort_t*)p;
  ushort_t* WffHi = Vbf;
  ushort_t* WffLo = Vbf + (size_t)DIMV * DIMV;
  p += MAT * 2;
  // R4 (32MB): Xbf; later outBf (split3 out)
  ushort_t* Xbf = (ushort_t*)p;
  ushort_t* outBf = Xbf;
  p += MAT * 2;
  float* denom = (float*)p;  p += (size_t)NHEADS * N_NODES * 4;
  float* v2sum = (float*)p;  p += 1024 * 4;
  float* ctxT = (float*)p;   p += (size_t)NHEADS * 4096 * 4;
  const size_t need = (size_t)(p - (char*)d_ws);
  if (ws_size < need) return;

  // W^T bf16 scratch inside d_out (free until the final rowtrans writes it):
  ushort_t* Wt = (ushort_t*)d_out;            // Wv^T, later Wq^T (rows 0..1023)
  ushort_t* WtK = Wt + (size_t)DIMV * DIMV;   // Wk^T (rows 1024..2047 of stacked QK)

  dim3 tgrid(32, 32);

  cvt_norm_kernel<<<N_NODES, 256, 0, stream>>>(X, Xbf, xnormsq);
  // V path: mxV bf16, then rowtrans -> Vbf + denom
  transW_kernel<false><<<tgrid, 256, 0, stream>>>(Wv, Wt, nullptr);
  gemm_bf<0, 8><<<1024, 256, 0, stream>>>(Xbf, Wt, nullptr, nullptr, nullptr, nullptr,
                                          nullptr, mxV, nullptr);
  rowtrans_kernel<true><<<N_NODES, 256, 0, stream>>>(mxV, xnormsq, Vbf, denom);
  // zero accumulators (v2sum+ctxT contiguous; combnorm over dead mxV)
  hipMemsetAsync(v2sum, 0, (1024 + 4096 * NHEADS) * sizeof(float), stream);
  hipMemsetAsync(combnorm, 0, N_NODES * sizeof(float), stream);
  // QK fused: stacked [Wq^T; Wk^T], epilogue emits v1 (cols<1024) and v2 + v2sum (cols>=1024)
  transW_kernel<false><<<tgrid, 256, 0, stream>>>(Wq, Wt, nullptr);
  transW_kernel<false><<<tgrid, 256, 0, stream>>>(Wk, WtK, nullptr);
  gemm_bf<3, 16><<<2048, 256, 0, stream>>>(Xbf, Wt, bq, bk, denom, mask, v2sum, v1bf, v2bf);
  // context (transposed output)
  context_kernel<<<dim3(32, NHEADS), 256, 0, stream>>>(v2bf, Vbf, denom, mask, ctxT);
  // attention out -> combHi/Lo + row norms
  out_mfma_kernel<<<dim3(N_NODES / 256, NHEADS), 256, 0, stream>>>(v1bf, v2sum, ctxT, combHi,
                                                                   combLo, combnorm);
  // final: fused 3-term split GEMM -> outBf, then rowtrans -> d_out
  transW_kernel<true><<<tgrid, 256, 0, stream>>>(Wff, WffHi, WffLo);
  gemm_split3<<<256, 512, 0, stream>>>(combHi, combLo, WffHi, WffLo, outBf);
  rowtrans_kernel<false><<<N_NODES, 256, 0, stream>>>(outBf, combnorm, out, nullptr);
}